// Round 3
// baseline (2780.480 us; speedup 1.0000x reference)
//
#include <hip/hip_runtime.h>
#include <cstdint>
#include <cstddef>

#define N_NODES 20000
#define N_EDGES 320000
#define EKCAP   (N_EDGES / 2)   // capacity (rows of 256) for kept-es1 in u1

__device__ __forceinline__ float frelu(float x){ return x > 0.f ? x : 0.f; }
__device__ __forceinline__ float fleaky(float x){ return x > 0.f ? x : 0.2f*x; }

__device__ __forceinline__ float wsum(float v){
  #pragma unroll
  for (int o = 32; o > 0; o >>= 1) v += __shfl_down(v, o);
  return v;
}
__device__ __forceinline__ float wmaxr(float v){
  #pragma unroll
  for (int o = 32; o > 0; o >>= 1) v = fmaxf(v, __shfl_down(v, o));
  return v;
}
__device__ __forceinline__ int wsumi(int v){
  #pragma unroll
  for (int o = 32; o > 0; o >>= 1) v += __shfl_down(v, o);
  return v;
}

// ---------------------------------------------------------------- sgemm (single out)
__global__ __launch_bounds__(256) void sgemm_k(
    const float* __restrict__ A1, int K1, const float* __restrict__ B1,
    const float* __restrict__ bias, float* __restrict__ C, int M, int Nn)
{
  __shared__ float As[16][68];
  __shared__ float Bs[16][64];
  const int t = threadIdx.x;
  const int m0 = blockIdx.y * 64, n0 = blockIdx.x * 64;
  const int tx = t & 15, ty = t >> 4;
  float acc[4][4] = {{0.f}};
  for (int kt = 0; kt < K1; kt += 16) {
    {
      const int row = t >> 2, k4 = (t & 3) * 4;
      const int gm = m0 + row;
      float4 v = make_float4(0.f, 0.f, 0.f, 0.f);
      if (gm < M) v = *(const float4*)(A1 + (size_t)gm * K1 + kt + k4);
      As[k4 + 0][row] = v.x; As[k4 + 1][row] = v.y;
      As[k4 + 2][row] = v.z; As[k4 + 3][row] = v.w;
      const int r = t >> 4, c4 = (t & 15) * 4;
      *(float4*)&Bs[r][c4] = *(const float4*)(B1 + (size_t)(kt + r) * Nn + n0 + c4);
    }
    __syncthreads();
    #pragma unroll
    for (int kk = 0; kk < 16; ++kk) {
      const float4 a = *(const float4*)&As[kk][ty * 4];
      const float4 b = *(const float4*)&Bs[kk][tx * 4];
      acc[0][0] += a.x * b.x; acc[0][1] += a.x * b.y; acc[0][2] += a.x * b.z; acc[0][3] += a.x * b.w;
      acc[1][0] += a.y * b.x; acc[1][1] += a.y * b.y; acc[1][2] += a.y * b.z; acc[1][3] += a.y * b.w;
      acc[2][0] += a.z * b.x; acc[2][1] += a.z * b.y; acc[2][2] += a.z * b.z; acc[2][3] += a.z * b.w;
      acc[3][0] += a.w * b.x; acc[3][1] += a.w * b.y; acc[3][2] += a.w * b.z; acc[3][3] += a.w * b.w;
    }
    __syncthreads();
  }
  float4 bv = make_float4(0.f, 0.f, 0.f, 0.f);
  if (bias) bv = *(const float4*)(bias + n0 + tx * 4);
  #pragma unroll
  for (int i = 0; i < 4; ++i) {
    const int gm = m0 + ty * 4 + i;
    if (gm >= M) continue;
    float4 o;
    o.x = acc[i][0] + bv.x; o.y = acc[i][1] + bv.y;
    o.z = acc[i][2] + bv.z; o.w = acc[i][3] + bv.w;
    *(float4*)(C + (size_t)gm * Nn + n0 + tx * 4) = o;
  }
}

// ---------------------------------------------------------------- sgemm, P/Q fused over z
// z=0: C=Ca, B=B?a, +bias. z=1: C=Cb, B=B?b, no bias. Dual-A (A2 optional).
__global__ __launch_bounds__(256) void sgemm2_k(
    const float* __restrict__ A1, int K1,
    const float* __restrict__ B1a, const float* __restrict__ B1b,
    const float* __restrict__ A2, int K2,
    const float* __restrict__ B2a, const float* __restrict__ B2b,
    const float* __restrict__ bias,
    float* __restrict__ Ca, float* __restrict__ Cb, int M, int Nn)
{
  __shared__ float As[16][68];
  __shared__ float Bs[16][64];
  const int z = blockIdx.z;
  const float* B1 = z ? B1b : B1a;
  const float* B2 = z ? B2b : B2a;
  float* C = z ? Cb : Ca;
  const float* bs = z ? nullptr : bias;
  const int t = threadIdx.x;
  const int m0 = blockIdx.y * 64, n0 = blockIdx.x * 64;
  const int tx = t & 15, ty = t >> 4;
  float acc[4][4] = {{0.f}};
  for (int pass = 0; pass < 2; ++pass) {
    const float* A = pass ? A2 : A1;
    const float* B = pass ? B2 : B1;
    const int K = pass ? K2 : K1;
    if (A == nullptr) continue;
    for (int kt = 0; kt < K; kt += 16) {
      {
        const int row = t >> 2, k4 = (t & 3) * 4;
        const int gm = m0 + row;
        float4 v = make_float4(0.f, 0.f, 0.f, 0.f);
        if (gm < M) v = *(const float4*)(A + (size_t)gm * K + kt + k4);
        As[k4 + 0][row] = v.x; As[k4 + 1][row] = v.y;
        As[k4 + 2][row] = v.z; As[k4 + 3][row] = v.w;
        const int r = t >> 4, c4 = (t & 15) * 4;
        *(float4*)&Bs[r][c4] = *(const float4*)(B + (size_t)(kt + r) * Nn + n0 + c4);
      }
      __syncthreads();
      #pragma unroll
      for (int kk = 0; kk < 16; ++kk) {
        const float4 a = *(const float4*)&As[kk][ty * 4];
        const float4 b = *(const float4*)&Bs[kk][tx * 4];
        acc[0][0] += a.x * b.x; acc[0][1] += a.x * b.y; acc[0][2] += a.x * b.z; acc[0][3] += a.x * b.w;
        acc[1][0] += a.y * b.x; acc[1][1] += a.y * b.y; acc[1][2] += a.y * b.z; acc[1][3] += a.y * b.w;
        acc[2][0] += a.z * b.x; acc[2][1] += a.z * b.y; acc[2][2] += a.z * b.z; acc[2][3] += a.z * b.w;
        acc[3][0] += a.w * b.x; acc[3][1] += a.w * b.y; acc[3][2] += a.w * b.z; acc[3][3] += a.w * b.w;
      }
      __syncthreads();
    }
  }
  float4 bv = make_float4(0.f, 0.f, 0.f, 0.f);
  if (bs) bv = *(const float4*)(bs + n0 + tx * 4);
  #pragma unroll
  for (int i = 0; i < 4; ++i) {
    const int gm = m0 + ty * 4 + i;
    if (gm >= M) continue;
    float4 o;
    o.x = acc[i][0] + bv.x; o.y = acc[i][1] + bv.y;
    o.z = acc[i][2] + bv.z; o.w = acc[i][3] + bv.w;
    *(float4*)(C + (size_t)gm * Nn + n0 + tx * 4) = o;
  }
}

#define FMA16(J) \
    acc[J][0] = fmaf(a.w, w3.x, fmaf(a.z, w2.x, fmaf(a.y, w1.x, fmaf(a.x, w0.x, acc[J][0])))); \
    acc[J][1] = fmaf(a.w, w3.y, fmaf(a.z, w2.y, fmaf(a.y, w1.y, fmaf(a.x, w0.y, acc[J][1])))); \
    acc[J][2] = fmaf(a.w, w3.z, fmaf(a.z, w2.z, fmaf(a.y, w1.z, fmaf(a.x, w0.z, acc[J][2])))); \
    acc[J][3] = fmaf(a.w, w3.w, fmaf(a.z, w2.w, fmaf(a.y, w1.w, fmaf(a.x, w0.w, acc[J][3]))));

// ---------------------------------------------------------------- edge conv
// m_e = ein_e @ We + P[src] + Q[dst]. Aggregates into xsum[dst] (edges sorted
// by dst -> run-compressed atomics). A-reads from LDS are wave-broadcast
// ds_read_b128 (k-vectorized); no pad needed. LDS: 128-out 40960 B (4 blk/CU),
// 256-out 32768 B (5 blk/CU).
template<int BE, int NOUT, bool RELUIN, bool GATHER, bool STOREM, bool WHEAD>
__global__ __launch_bounds__(256, 4) void econv_k(
    const float* __restrict__ ein0, const float* __restrict__ ein1,
    const float* __restrict__ We,
    const float* __restrict__ P, const float* __restrict__ Q,
    const int* __restrict__ ssrc, const int* __restrict__ sdst,
    const int* __restrict__ seid,
    float* __restrict__ mout0, float* __restrict__ mout1,
    float* __restrict__ xsum,
    const float* __restrict__ wvec, const float* __restrict__ wb,
    float* __restrict__ outw)
{
  constexpr int NC4 = NOUT / 4;     // 32 or 64
  constexpr int TE  = 256 / NC4;
  constexpr int EPT = BE / TE;      // 8 in both configs
  __shared__ float As[BE * 128];
  __shared__ float Ws[16 * NOUT];
  const int t = threadIdx.x;
  const int base = blockIdx.x * BE;
  const int tx = t % NC4, te = t / NC4;
  const int e0 = te * EPT;
  float acc[EPT][4];
  #pragma unroll
  for (int j = 0; j < EPT; ++j) { acc[j][0] = 0.f; acc[j][1] = 0.f; acc[j][2] = 0.f; acc[j][3] = 0.f; }
  const int nbuf = (ein1 != nullptr) ? 2 : 1;
  for (int buf = 0; buf < nbuf; ++buf) {
    const float* ein = buf ? ein1 : ein0;
    __syncthreads();
    #pragma unroll
    for (int i = t; i < BE * 32; i += 256) {
      const int e = i >> 5, k4 = (i & 31) * 4;
      const int g = base + e;
      const size_t row = GATHER ? (size_t)seid[g] : (size_t)g;
      float4 v = *(const float4*)(ein + row * 128 + k4);
      if (RELUIN) { v.x = frelu(v.x); v.y = frelu(v.y); v.z = frelu(v.z); v.w = frelu(v.w); }
      *(float4*)&As[e * 128 + k4] = v;
    }
    for (int chunk = 0; chunk < 8; ++chunk) {
      __syncthreads();
      #pragma unroll
      for (int i = t; i < 16 * NC4; i += 256) {
        const int r = i / NC4, c4 = (i % NC4) * 4;
        *(float4*)&Ws[r * NOUT + c4] =
            *(const float4*)(We + (size_t)(buf * 128 + chunk * 16 + r) * NOUT + c4);
      }
      __syncthreads();
      #pragma unroll
      for (int kk = 0; kk < 16; kk += 4) {
        const float4 w0 = *(const float4*)&Ws[(kk + 0) * NOUT + tx * 4];
        const float4 w1 = *(const float4*)&Ws[(kk + 1) * NOUT + tx * 4];
        const float4 w2 = *(const float4*)&Ws[(kk + 2) * NOUT + tx * 4];
        const float4 w3 = *(const float4*)&Ws[(kk + 3) * NOUT + tx * 4];
        #pragma unroll
        for (int j = 0; j < EPT; ++j) {
          const float4 a = *(const float4*)&As[(e0 + j) * 128 + chunk * 16 + kk];
          FMA16(j)
        }
      }
    }
  }
  float4 wv = make_float4(0.f, 0.f, 0.f, 0.f);
  if constexpr (WHEAD) wv = *(const float4*)(wvec + tx * 4);
  int cur = sdst[base + e0];
  float r0 = 0.f, r1 = 0.f, r2 = 0.f, r3 = 0.f;
  #pragma unroll
  for (int j = 0; j < EPT; ++j) {
    const int g = base + e0 + j;
    const int s = ssrc[g], d = sdst[g];
    const float4 p = *(const float4*)(P + (size_t)s * NOUT + tx * 4);
    const float4 q = *(const float4*)(Q + (size_t)d * NOUT + tx * 4);
    float4 m;
    m.x = acc[j][0] + p.x + q.x; m.y = acc[j][1] + p.y + q.y;
    m.z = acc[j][2] + p.z + q.z; m.w = acc[j][3] + p.w + q.w;
    if constexpr (STOREM) {
      const int c = tx * 4;
      if (NOUT == 128) {
        *(float4*)(mout0 + (size_t)g * 128 + c) = m;
      } else {
        if (c < 128) *(float4*)(mout0 + (size_t)g * 128 + c) = m;
        else         *(float4*)(mout1 + (size_t)g * 128 + (c - 128)) = m;
      }
    }
    if constexpr (WHEAD) {
      float wp = frelu(m.x) * wv.x + frelu(m.y) * wv.y + frelu(m.z) * wv.z + frelu(m.w) * wv.w;
      #pragma unroll
      for (int o = 16; o > 0; o >>= 1) wp += __shfl_down(wp, o);
      if (tx == 0) outw[seid[g]] = 1.f / (1.f + expf(-(wp + wb[0])));
    }
    if (d != cur) {
      float* xs = xsum + (size_t)cur * NOUT + tx * 4;
      atomicAdd(xs + 0, r0); atomicAdd(xs + 1, r1);
      atomicAdd(xs + 2, r2); atomicAdd(xs + 3, r3);
      cur = d; r0 = r1 = r2 = r3 = 0.f;
    }
    r0 += m.x; r1 += m.y; r2 += m.z; r3 += m.w;
  }
  {
    float* xs = xsum + (size_t)cur * NOUT + tx * 4;
    atomicAdd(xs + 0, r0); atomicAdd(xs + 1, r1);
    atomicAdd(xs + 2, r2); atomicAdd(xs + 3, r3);
  }
}

// ---------------------------------------------------------------- presub:
// recompute es1 for kept edges only: es1_i = relu(relu(e3[cidx])@We + P[src]+Q[dst])
__global__ __launch_bounds__(256, 4) void presub_k(
    const float* __restrict__ e3buf, const float* __restrict__ We,
    const float* __restrict__ P, const float* __restrict__ Q,
    const int* __restrict__ csrc, const int* __restrict__ cdst,
    const int* __restrict__ cidx, const int* __restrict__ nKp,
    float* __restrict__ es1out)  // row stride 256
{
  constexpr int BE = 32;
  const int nK = min(*nKp, EKCAP);
  const int base = blockIdx.x * BE;
  if (base >= nK) return;
  __shared__ float As[BE * 128];
  __shared__ float Ws[16 * 256];
  const int t = threadIdx.x;
  const int tx = t & 63, te = t >> 6;
  const int e0 = te * 8;
  float acc[8][4];
  #pragma unroll
  for (int j = 0; j < 8; ++j) { acc[j][0] = 0.f; acc[j][1] = 0.f; acc[j][2] = 0.f; acc[j][3] = 0.f; }
  #pragma unroll
  for (int i = t; i < BE * 32; i += 256) {
    const int e = i >> 5, k4 = (i & 31) * 4;
    const int g = base + e;
    const size_t row = (g < nK) ? (size_t)cidx[g] : 0;
    float4 v = *(const float4*)(e3buf + row * 128 + k4);
    v.x = frelu(v.x); v.y = frelu(v.y); v.z = frelu(v.z); v.w = frelu(v.w);
    *(float4*)&As[e * 128 + k4] = v;
  }
  for (int chunk = 0; chunk < 8; ++chunk) {
    __syncthreads();
    #pragma unroll
    for (int i = t; i < 16 * 64; i += 256) {
      const int r = i >> 6, c4 = (i & 63) * 4;
      *(float4*)&Ws[r * 256 + c4] = *(const float4*)(We + (size_t)(chunk * 16 + r) * 256 + c4);
    }
    __syncthreads();
    #pragma unroll
    for (int kk = 0; kk < 16; kk += 4) {
      const float4 w0 = *(const float4*)&Ws[(kk + 0) * 256 + tx * 4];
      const float4 w1 = *(const float4*)&Ws[(kk + 1) * 256 + tx * 4];
      const float4 w2 = *(const float4*)&Ws[(kk + 2) * 256 + tx * 4];
      const float4 w3 = *(const float4*)&Ws[(kk + 3) * 256 + tx * 4];
      #pragma unroll
      for (int j = 0; j < 8; ++j) {
        const float4 a = *(const float4*)&As[(e0 + j) * 128 + chunk * 16 + kk];
        FMA16(j)
      }
    }
  }
  #pragma unroll
  for (int j = 0; j < 8; ++j) {
    const int g = base + e0 + j;
    if (g < nK) {
      const int s = csrc[g], d = cdst[g];
      const float4 p = *(const float4*)(P + (size_t)s * 256 + tx * 4);
      const float4 q = *(const float4*)(Q + (size_t)d * 256 + tx * 4);
      float4 o;
      o.x = frelu(acc[j][0] + p.x + q.x); o.y = frelu(acc[j][1] + p.y + q.y);
      o.z = frelu(acc[j][2] + p.z + q.z); o.w = frelu(acc[j][3] + p.w + q.w);
      *(float4*)(es1out + (size_t)g * 256 + tx * 4) = o;
    }
  }
}

// ---------------------------------------------------------------- sub conv stage 2
__global__ __launch_bounds__(256, 4) void subconv_k(
    const float* __restrict__ es1, const float* __restrict__ We,
    const float* __restrict__ P, const float* __restrict__ Q,
    const int* __restrict__ csrc, const int* __restrict__ cdst,
    const int* __restrict__ nKp, float* __restrict__ xsum)
{
  constexpr int BE = 64;
  const int nK = min(*nKp, EKCAP);
  const int base = blockIdx.x * BE;
  if (base >= nK) return;
  __shared__ float As[BE * 128];
  __shared__ float Ws[16 * 128];
  const int t = threadIdx.x;
  const int tx = t & 31, te = t >> 5;
  const int e0 = te * 8;
  float acc[8][4];
  #pragma unroll
  for (int j = 0; j < 8; ++j) { acc[j][0] = 0.f; acc[j][1] = 0.f; acc[j][2] = 0.f; acc[j][3] = 0.f; }
  for (int buf = 0; buf < 2; ++buf) {
    __syncthreads();
    #pragma unroll
    for (int i = t; i < BE * 32; i += 256) {
      const int e = i >> 5, k4 = (i & 31) * 4;
      const size_t row = (size_t)(base + e);
      *(float4*)&As[e * 128 + k4] = *(const float4*)(es1 + row * 256 + buf * 128 + k4);
    }
    for (int chunk = 0; chunk < 8; ++chunk) {
      __syncthreads();
      #pragma unroll
      for (int i = t; i < 16 * 32; i += 256) {
        const int r = i >> 5, c4 = (i & 31) * 4;
        *(float4*)&Ws[r * 128 + c4] =
            *(const float4*)(We + (size_t)(buf * 128 + chunk * 16 + r) * 128 + c4);
      }
      __syncthreads();
      #pragma unroll
      for (int kk = 0; kk < 16; kk += 4) {
        const float4 w0 = *(const float4*)&Ws[(kk + 0) * 128 + tx * 4];
        const float4 w1 = *(const float4*)&Ws[(kk + 1) * 128 + tx * 4];
        const float4 w2 = *(const float4*)&Ws[(kk + 2) * 128 + tx * 4];
        const float4 w3 = *(const float4*)&Ws[(kk + 3) * 128 + tx * 4];
        #pragma unroll
        for (int j = 0; j < 8; ++j) {
          const float4 a = *(const float4*)&As[(e0 + j) * 128 + chunk * 16 + kk];
          FMA16(j)
        }
      }
    }
  }
  int cur = -1;
  float r0 = 0.f, r1 = 0.f, r2 = 0.f, r3 = 0.f;
  #pragma unroll
  for (int j = 0; j < 8; ++j) {
    const int g = base + e0 + j;
    if (g < nK) {
      const int s = csrc[g], d = cdst[g];
      const float4 p = *(const float4*)(P + (size_t)s * 128 + tx * 4);
      const float4 q = *(const float4*)(Q + (size_t)d * 128 + tx * 4);
      const float mx = acc[j][0] + p.x + q.x, my = acc[j][1] + p.y + q.y;
      const float mz = acc[j][2] + p.z + q.z, mw = acc[j][3] + p.w + q.w;
      if (d != cur) {
        if (cur >= 0) {
          float* xs = xsum + (size_t)cur * 128 + tx * 4;
          atomicAdd(xs + 0, r0); atomicAdd(xs + 1, r1);
          atomicAdd(xs + 2, r2); atomicAdd(xs + 3, r3);
        }
        cur = d; r0 = r1 = r2 = r3 = 0.f;
      }
      r0 += mx; r1 += my; r2 += mz; r3 += mw;
    }
  }
  if (cur >= 0) {
    float* xs = xsum + (size_t)cur * 128 + tx * 4;
    atomicAdd(xs + 0, r0); atomicAdd(xs + 1, r1);
    atomicAdd(xs + 2, r2); atomicAdd(xs + 3, r3);
  }
}

// ---------------------------------------------------------------- small kernels
__global__ void hist_k(const int* __restrict__ dst, int* __restrict__ deg, int E){
  const int e = blockIdx.x * 256 + threadIdx.x;
  if (e < E) atomicAdd(&deg[dst[e]], 1);
}

__global__ __launch_bounds__(1024) void scan_deg_k(
    const int* __restrict__ deg, int* __restrict__ rowstart, int* __restrict__ cursor,
    float* __restrict__ recip, int n)
{
  __shared__ int sb[1024];
  __shared__ int carry;
  const int t = threadIdx.x;
  if (t == 0) carry = 0;
  __syncthreads();
  const int CH = (n + 1023) >> 10;
  for (int c = 0; c < CH; ++c) {
    const int i = c * 1024 + t;
    const int d = (i < n) ? deg[i] : 0;
    sb[t] = d;
    __syncthreads();
    for (int off = 1; off < 1024; off <<= 1) {
      const int v = (t >= off) ? sb[t - off] : 0;
      __syncthreads();
      sb[t] += v;
      __syncthreads();
    }
    const int excl = sb[t] - d;
    const int tot = sb[1023];
    if (i < n) {
      const int rs = carry + excl;
      rowstart[i] = rs; cursor[i] = rs;
      recip[i] = 1.0f / (float)max(d, 1);
    }
    __syncthreads();
    if (t == 0) carry += tot;
    __syncthreads();
  }
  if (t == 0) rowstart[n] = carry;
}

__global__ void scatter_k(const int* __restrict__ src, const int* __restrict__ dst,
                          int* __restrict__ cursor, int* __restrict__ ssrc,
                          int* __restrict__ sdst, int* __restrict__ seid, int E){
  const int e = blockIdx.x * 256 + threadIdx.x;
  if (e < E) {
    const int d = dst[e];
    const int pos = atomicAdd(&cursor[d], 1);
    ssrc[pos] = src[e]; sdst[pos] = d; seid[pos] = e;
  }
}

__global__ void meanrelu_k(const float* __restrict__ xsum, const float* __restrict__ recip,
                           float* __restrict__ out, int total, int shift){
  const int i = blockIdx.x * 256 + threadIdx.x;
  if (i < total) out[i] = frelu(xsum[i] * recip[i >> shift]);
}

__global__ void h_k(const float* __restrict__ xs1, const float* __restrict__ Wg,
                    float* __restrict__ h, int n){
  const int node = blockIdx.x * 4 + (threadIdx.x >> 6);
  const int lane = threadIdx.x & 63;
  if (node >= n) return;
  const float4 x = *(const float4*)(xs1 + (size_t)node * 256 + lane * 4);
  const float4 w = *(const float4*)(Wg + lane * 4);
  float v = x.x * w.x + x.y * w.y + x.z * w.z + x.w * w.w;
  v = wsum(v);
  if (lane == 0) h[node] = v;
}

__global__ void att_k(const float* __restrict__ h, const int* __restrict__ rowstart,
                      const int* __restrict__ ssrc, const float* __restrict__ asp,
                      const float* __restrict__ adp, float* __restrict__ score, int n){
  const int node = blockIdx.x * 4 + (threadIdx.x >> 6);
  const int lane = threadIdx.x & 63;
  if (node >= n) return;
  const float a_s = asp[0], a_d = adp[0];
  const float hv = h[node];
  const int s0 = rowstart[node], s1 = rowstart[node + 1];
  const float selfea = fleaky(hv * (a_s + a_d));
  float mx = selfea;
  for (int i = s0 + lane; i < s1; i += 64) {
    const float hs = h[ssrc[i]];
    mx = fmaxf(mx, fleaky(hs * a_s + hv * a_d));
  }
  mx = wmaxr(mx);
  mx = __shfl(mx, 0);
  float den = 0.f, num = 0.f;
  if (lane == 0) { const float ez = expf(selfea - mx); den = ez; num = ez * hv; }
  for (int i = s0 + lane; i < s1; i += 64) {
    const float hs = h[ssrc[i]];
    const float ez = expf(fleaky(hs * a_s + hv * a_d) - mx);
    den += ez; num += ez * hs;
  }
  den = wsum(den); num = wsum(num);
  if (lane == 0) score[node] = num / den;
}

__device__ __forceinline__ unsigned keymap(float s){
  unsigned u = __float_as_uint(s);
  return (u & 0x80000000u) ? ~u : (u | 0x80000000u);
}

__global__ __launch_bounds__(1024) void topk_k(const float* __restrict__ score,
                                               int* __restrict__ kept,
                                               float* __restrict__ tfac, int n, int k)
{
  const int t = threadIdx.x;
  constexpr int CH = 20;  // covers n <= 20480
  unsigned key[CH];
  float sc[CH];
  #pragma unroll
  for (int c = 0; c < CH; ++c) {
    const int i = c * 1024 + t;
    if (i < n) { const float s = score[i]; sc[c] = s; key[c] = keymap(s); }
    else       { sc[c] = 0.f; key[c] = 0u; }
  }
  __shared__ int cnt;
  __shared__ int sb[1024];
  __shared__ int carry_eq;
  unsigned vstar = 0u;
  for (int b = 31; b >= 0; --b) {
    const unsigned cand = vstar | (1u << b);
    if (t == 0) cnt = 0;
    __syncthreads();
    int local = 0;
    #pragma unroll
    for (int c = 0; c < CH; ++c) local += (key[c] >= cand) ? 1 : 0;
    local = wsumi(local);
    if ((t & 63) == 0) atomicAdd(&cnt, local);
    __syncthreads();
    if (cnt >= k) vstar = cand;
    __syncthreads();
  }
  if (t == 0) cnt = 0;
  __syncthreads();
  {
    int local = 0;
    #pragma unroll
    for (int c = 0; c < CH; ++c) local += (key[c] > vstar) ? 1 : 0;
    local = wsumi(local);
    if ((t & 63) == 0) atomicAdd(&cnt, local);
  }
  __syncthreads();
  const int need = k - cnt;  // ties kept by lowest index
  if (t == 0) carry_eq = 0;
  __syncthreads();
  for (int c = 0; c < CH; ++c) {
    const int i = c * 1024 + t;
    const int flag = (i < n && key[c] == vstar) ? 1 : 0;
    sb[t] = flag;
    __syncthreads();
    for (int off = 1; off < 1024; off <<= 1) {
      const int v = (t >= off) ? sb[t - off] : 0;
      __syncthreads();
      sb[t] += v;
      __syncthreads();
    }
    const int rank = sb[t] - flag;
    const int tot = sb[1023];
    if (i < n) {
      const bool kp = (key[c] > vstar) || (flag && (carry_eq + rank) < need);
      kept[i] = kp ? 1 : 0;
      tfac[i] = kp ? tanhf(sc[c]) : 0.f;
    }
    __syncthreads();
    if (t == 0) carry_eq += tot;
    __syncthreads();
  }
}

__global__ void xpip_k(float* __restrict__ xs1, const float* __restrict__ tf, int total){
  const int i = blockIdx.x * 256 + threadIdx.x;
  if (i < total) xs1[i] *= tf[i >> 8];
}

__global__ __launch_bounds__(256) void flagsum_k(const int* __restrict__ kept,
    const int* __restrict__ ssrc, const int* __restrict__ sdst,
    int* __restrict__ bsum, int E){
  const int t = threadIdx.x;
  const int base = blockIdx.x * 1024;
  int loc = 0;
  #pragma unroll
  for (int j = 0; j < 4; ++j) {
    const int e = base + t * 4 + j;
    if (e < E) loc += kept[ssrc[e]] & kept[sdst[e]];
  }
  loc = wsumi(loc);
  __shared__ int wsh[4];
  if ((t & 63) == 0) wsh[t >> 6] = loc;
  __syncthreads();
  if (t == 0) bsum[blockIdx.x] = wsh[0] + wsh[1] + wsh[2] + wsh[3];
}

__global__ __launch_bounds__(512) void scanb_k(int* __restrict__ bsum, int nb, int* __restrict__ Ek){
  __shared__ int sb[512];
  const int t = threadIdx.x;
  const int v = (t < nb) ? bsum[t] : 0;
  sb[t] = v;
  __syncthreads();
  for (int off = 1; off < 512; off <<= 1) {
    const int u = (t >= off) ? sb[t - off] : 0;
    __syncthreads();
    sb[t] += u;
    __syncthreads();
  }
  if (t < nb) bsum[t] = sb[t] - v;   // exclusive
  if (t == 511) *Ek = sb[511];
}

__global__ __launch_bounds__(256) void compact_k(const int* __restrict__ kept,
    const int* __restrict__ ssrc, const int* __restrict__ sdst,
    const int* __restrict__ bsum, int* __restrict__ csrc, int* __restrict__ cdst,
    int* __restrict__ cidx, int* __restrict__ cntk, int E){
  const int t = threadIdx.x;
  const int base = blockIdx.x * 1024;
  int f[4]; int s = 0;
  #pragma unroll
  for (int j = 0; j < 4; ++j) {
    const int e = base + t * 4 + j;
    f[j] = (e < E) ? (kept[ssrc[e]] & kept[sdst[e]]) : 0;
    s += f[j];
  }
  __shared__ int sb[256];
  sb[t] = s;
  __syncthreads();
  for (int off = 1; off < 256; off <<= 1) {
    const int u = (t >= off) ? sb[t - off] : 0;
    __syncthreads();
    sb[t] += u;
    __syncthreads();
  }
  int pos = bsum[blockIdx.x] + sb[t] - s;
  #pragma unroll
  for (int j = 0; j < 4; ++j) {
    if (f[j]) {
      const int e = base + t * 4 + j;
      csrc[pos] = ssrc[e]; cdst[pos] = sdst[e]; cidx[pos] = e;
      atomicAdd(&cntk[sdst[e]], 1);
      ++pos;
    }
  }
}

__global__ void submerge_k(const float* __restrict__ x3, const float* __restrict__ xsum,
                           const int* __restrict__ cntk, const int* __restrict__ kept,
                           float* __restrict__ x32, int total){
  const int i = blockIdx.x * 256 + threadIdx.x;
  if (i >= total) return;
  const int v = i >> 7;
  float add = 0.f;
  if (kept[v]) {
    float c = (float)cntk[v];
    c = c > 0.f ? c : 1.f;
    add = frelu(xsum[i] / c);
  }
  x32[i] = x3[i] + add;
}

__global__ void fnode_k(const float* __restrict__ xsum, const float* __restrict__ recip,
                        const float* __restrict__ Wl1, const float* __restrict__ bl1,
                        float* __restrict__ out, int n){
  const int node = blockIdx.x * 4 + (threadIdx.x >> 6);
  const int lane = threadIdx.x & 63;
  if (node >= n) return;
  const float rc = recip[node];
  const float2 xv = *(const float2*)(xsum + (size_t)node * 128 + lane * 2);
  const float2 wv = *(const float2*)(Wl1 + lane * 2);
  float v = frelu(xv.x * rc) * wv.x + frelu(xv.y * rc) * wv.y;
  v = wsum(v);
  if (lane == 0) out[node] = 1.f / (1.f + expf(-(v + bl1[0])));
}

// ---------------------------------------------------------------- launch
extern "C" void kernel_launch(void* const* d_in, const int* in_sizes, int n_in,
                              void* d_out, int out_size, void* d_ws, size_t ws_size,
                              hipStream_t stream)
{
  const int N = N_NODES, E = N_EDGES;
  const float* node_feat = (const float*)d_in[0];
  const float* edge_feat = (const float*)d_in[1];
  const int*   eidx      = (const int*)d_in[2];
  const float* W_red = (const float*)d_in[3];  const float* b_red = (const float*)d_in[4];
  const float* W1 = (const float*)d_in[5];   const float* b1 = (const float*)d_in[6];
  const float* W2 = (const float*)d_in[7];   const float* b2 = (const float*)d_in[8];
  const float* W3 = (const float*)d_in[9];   const float* b3 = (const float*)d_in[10];
  const float* Wpre = (const float*)d_in[11]; const float* bpre = (const float*)d_in[12];
  const float* Wsub = (const float*)d_in[13]; const float* bsub = (const float*)d_in[14];
  const float* W4 = (const float*)d_in[15];  const float* b4 = (const float*)d_in[16];
  const float* Wg = (const float*)d_in[17];
  const float* a_s = (const float*)d_in[18]; const float* a_d = (const float*)d_in[19];
  const float* Wl1 = (const float*)d_in[20]; const float* bl1 = (const float*)d_in[21];
  const float* Ww = (const float*)d_in[22];  const float* bw = (const float*)d_in[23];
  float* out_x = (float*)d_out;
  float* out_w = out_x + N;

  char* wsb = (char*)d_ws;
  size_t off = 0;
  auto alloc = [&](size_t bytes) -> void* {
    void* p = wsb + off;
    off = (off + bytes + 255) & ~(size_t)255;
    return p;
  };
  // total ~449 MB
  float* u1   = (float*)alloc((size_t)E * 128 * 4);   // e1 -> e3a -> kept-es1(256-stride)
  float* u2   = (float*)alloc((size_t)E * 128 * 4);   // e2 -> e3
  float* n1   = (float*)alloc((size_t)N * 128 * 4);   // x0 -> x3a -> Psub -> x32
  float* n2   = (float*)alloc((size_t)N * 128 * 4);   // x1 -> x3
  float* n3   = (float*)alloc((size_t)N * 128 * 4);   // x2 -> Qsub
  float* xs1  = (float*)alloc((size_t)N * 256 * 4);   // xs1 -> xp (in place)
  float* P    = (float*)alloc((size_t)N * 256 * 4);
  float* Qb   = (float*)alloc((size_t)N * 256 * 4);
  float* xsum = (float*)alloc((size_t)N * 256 * 4);
  int* ssrc = (int*)alloc((size_t)E * 4);
  int* sdst = (int*)alloc((size_t)E * 4);
  int* seid = (int*)alloc((size_t)E * 4);
  int* csrc = (int*)alloc((size_t)E * 4);
  int* cdst = (int*)alloc((size_t)E * 4);
  int* cidx = (int*)alloc((size_t)E * 4);
  int* deg     = (int*)alloc((size_t)N * 4);
  int* cursor  = (int*)alloc((size_t)N * 4);
  int* rowstart= (int*)alloc((size_t)(N + 1) * 4);
  int* kept    = (int*)alloc((size_t)N * 4);
  int* cntk    = (int*)alloc((size_t)N * 4);
  float* recip = (float*)alloc((size_t)N * 4);
  float* hbuf  = (float*)alloc((size_t)N * 4);
  float* score = (float*)alloc((size_t)N * 4);
  float* tfac  = (float*)alloc((size_t)N * 4);
  int* bsum    = (int*)alloc(1024 * 4);
  int* Ek      = (int*)alloc(256);
  (void)ws_size; (void)in_sizes; (void)n_in; (void)out_size;

  const dim3 g128z(2, (N + 63) / 64, 2), g256z(4, (N + 63) / 64, 2);
  const dim3 g128(2, (N + 63) / 64);
  const int nbFS = (E + 1023) / 1024;
  #define NILS nullptr, nullptr, nullptr

  // ---- sort edges by dst (counting sort) ----
  hipMemsetAsync(deg, 0, (size_t)N * 4, stream);
  hist_k<<<(E + 255) / 256, 256, 0, stream>>>(eidx + E, deg, E);
  scan_deg_k<<<1, 1024, 0, stream>>>(deg, rowstart, cursor, recip, N);
  scatter_k<<<(E + 255) / 256, 256, 0, stream>>>(eidx, eidx + E, cursor, ssrc, sdst, seid, E);

  // ---- x0 = node_feat @ W_red + b_red -> n1 ----
  sgemm_k<<<g128, 256, 0, stream>>>(node_feat, 256, W_red, b_red, n1, N, 128);

  // ---- conv1: e in edge_feat, out u1; x1 -> n2 ----
  sgemm2_k<<<g128z, 256, 0, stream>>>(n1, 128, W1, W1 + 128 * 128,
                                      nullptr, 0, nullptr, nullptr, b1, P, Qb, N, 128);
  hipMemsetAsync(xsum, 0, (size_t)N * 128 * 4, stream);
  econv_k<64, 128, false, true, true, false><<<E / 64, 256, 0, stream>>>(
      edge_feat, nullptr, W1 + 256 * 128, P, Qb, ssrc, sdst, seid, u1, nullptr, xsum, NILS);
  meanrelu_k<<<(N * 128) / 256, 256, 0, stream>>>(xsum, recip, n2, N * 128, 7);

  // ---- conv2: in u1(e1), out u2; x2 -> n3 ----
  sgemm2_k<<<g128z, 256, 0, stream>>>(n2, 128, W2, W2 + 128 * 128,
                                      nullptr, 0, nullptr, nullptr, b2, P, Qb, N, 128);
  hipMemsetAsync(xsum, 0, (size_t)N * 128 * 4, stream);
  econv_k<64, 128, true, false, true, false><<<E / 64, 256, 0, stream>>>(
      u1, nullptr, W2 + 256 * 128, P, Qb, ssrc, sdst, seid, u2, nullptr, xsum, NILS);
  meanrelu_k<<<(N * 128) / 256, 256, 0, stream>>>(xsum, recip, n3, N * 128, 7);

  // ---- conv3 (first): xin=[x2,x1], ein=[e2,e1]; e3a overwrites u1 in place; x3a -> n1 ----
  sgemm2_k<<<g128z, 256, 0, stream>>>(n3, 128, W3, W3 + 256 * 128,
                                      n2, 128, W3 + 128 * 128, W3 + 384 * 128, b3, P, Qb, N, 128);
  hipMemsetAsync(xsum, 0, (size_t)N * 128 * 4, stream);
  econv_k<64, 128, true, false, true, false><<<E / 64, 256, 0, stream>>>(
      u2, u1, W3 + 512 * 128, P, Qb, ssrc, sdst, seid, u1, nullptr, xsum, NILS);
  meanrelu_k<<<(N * 128) / 256, 256, 0, stream>>>(xsum, recip, n1, N * 128, 7);

  // ---- conv3 (second, shared W3): xin=[x3a,x2], ein=[e3a,e2]; e3 overwrites u2; x3 -> n2 ----
  sgemm2_k<<<g128z, 256, 0, stream>>>(n1, 128, W3, W3 + 256 * 128,
                                      n3, 128, W3 + 128 * 128, W3 + 384 * 128, b3, P, Qb, N, 128);
  hipMemsetAsync(xsum, 0, (size_t)N * 128 * 4, stream);
  econv_k<64, 128, true, false, true, false><<<E / 64, 256, 0, stream>>>(
      u1, u2, W3 + 512 * 128, P, Qb, ssrc, sdst, seid, u2, nullptr, xsum, NILS);
  meanrelu_k<<<(N * 128) / 256, 256, 0, stream>>>(xsum, recip, n2, N * 128, 7);

  // ---- pre conv (NOUT=256), aggregate only (es1 NOT stored); xs1 ----
  sgemm2_k<<<g256z, 256, 0, stream>>>(n2, 128, Wpre, Wpre + 128 * 256,
                                      nullptr, 0, nullptr, nullptr, bpre, P, Qb, N, 256);
  hipMemsetAsync(xsum, 0, (size_t)N * 256 * 4, stream);
  econv_k<32, 256, true, false, false, false><<<E / 32, 256, 0, stream>>>(
      u2, nullptr, Wpre + 256 * 256, P, Qb, ssrc, sdst, seid, nullptr, nullptr, xsum, NILS);
  meanrelu_k<<<(N * 256) / 256, 256, 0, stream>>>(xsum, recip, xs1, N * 256, 8);

  // ---- SAGPool scorer + top-k; xp in-place over xs1 ----
  h_k<<<(N + 3) / 4, 256, 0, stream>>>(xs1, Wg, hbuf, N);
  att_k<<<(N + 3) / 4, 256, 0, stream>>>(hbuf, rowstart, ssrc, a_s, a_d, score, N);
  topk_k<<<1, 1024, 0, stream>>>(score, kept, tfac, N, N / 2);
  xpip_k<<<(N * 256) / 256, 256, 0, stream>>>(xs1, tfac, N * 256);

  // ---- compact kept edges ----
  hipMemsetAsync(cntk, 0, (size_t)N * 4, stream);
  flagsum_k<<<nbFS, 256, 0, stream>>>(kept, ssrc, sdst, bsum, E);
  scanb_k<<<1, 512, 0, stream>>>(bsum, nbFS, Ek);
  compact_k<<<nbFS, 256, 0, stream>>>(kept, ssrc, sdst, bsum, csrc, cdst, cidx, cntk, E);

  // ---- sub conv: Psub -> n1 (x3a dead), Qsub -> n3 (x2 dead) ----
  sgemm2_k<<<g128z, 256, 0, stream>>>(xs1, 256, Wsub, Wsub + 256 * 128,
                                      nullptr, 0, nullptr, nullptr, bsub, n1, n3, N, 128);
  // recompute es1 for kept edges into u1 (e3a dead); P/Qb still hold Ppre/Qpre
  presub_k<<<(EKCAP + 31) / 32, 256, 0, stream>>>(
      u2, Wpre + 256 * 256, P, Qb, csrc, cdst, cidx, Ek, u1);
  hipMemsetAsync(xsum, 0, (size_t)N * 128 * 4, stream);
  subconv_k<<<(EKCAP + 63) / 64, 256, 0, stream>>>(
      u1, Wsub + 512 * 128, n1, n3, csrc, cdst, Ek, xsum);
  submerge_k<<<(N * 128) / 256, 256, 0, stream>>>(n2, xsum, cntk, kept, n1, N * 128);

  // ---- conv4: xin=[x3_2(n1), x3(n2)], ein=e3(u2); fused w-head, no m store ----
  sgemm2_k<<<g128z, 256, 0, stream>>>(n1, 128, W4, W4 + 256 * 128,
                                      n2, 128, W4 + 128 * 128, W4 + 384 * 128, b4, P, Qb, N, 128);
  hipMemsetAsync(xsum, 0, (size_t)N * 128 * 4, stream);
  econv_k<64, 128, true, false, false, true><<<E / 64, 256, 0, stream>>>(
      u2, nullptr, W4 + 512 * 128, P, Qb, ssrc, sdst, seid, nullptr, nullptr, xsum, Ww, bw, out_w);

  // ---- node head ----
  fnode_k<<<(N + 3) / 4, 256, 0, stream>>>(xsum, recip, Wl1, bl1, out_x, N);
  #undef NILS
}

// Round 4
// 2592.326 us; speedup vs baseline: 1.0726x; 1.0726x over previous
//
#include <hip/hip_runtime.h>
#include <cstdint>
#include <cstddef>

#define N_NODES 20000
#define N_EDGES 320000
#define EKCAP   (N_EDGES / 2)

__device__ __forceinline__ float frelu(float x){ return x > 0.f ? x : 0.f; }
__device__ __forceinline__ float fleaky(float x){ return x > 0.f ? x : 0.2f*x; }

__device__ __forceinline__ float wsum(float v){
  #pragma unroll
  for (int o = 32; o > 0; o >>= 1) v += __shfl_down(v, o);
  return v;
}
__device__ __forceinline__ float wmaxr(float v){
  #pragma unroll
  for (int o = 32; o > 0; o >>= 1) v = fmaxf(v, __shfl_down(v, o));
  return v;
}
__device__ __forceinline__ int wsumi(int v){
  #pragma unroll
  for (int o = 32; o > 0; o >>= 1) v += __shfl_down(v, o);
  return v;
}
__device__ __forceinline__ float4 fma4(float s, float4 b, float4 c){
  c.x = fmaf(s, b.x, c.x); c.y = fmaf(s, b.y, c.y);
  c.z = fmaf(s, b.z, c.z); c.w = fmaf(s, b.w, c.w); return c;
}

// ---------------------------------------------------------------- sgemm (single out)
__global__ __launch_bounds__(256) void sgemm_k(
    const float* __restrict__ A1, int K1, const float* __restrict__ B1,
    const float* __restrict__ bias, float* __restrict__ C, int M, int Nn)
{
  __shared__ float As[16][68];
  __shared__ float Bs[16][64];
  const int t = threadIdx.x;
  const int m0 = blockIdx.y * 64, n0 = blockIdx.x * 64;
  const int tx = t & 15, ty = t >> 4;
  float acc[4][4] = {{0.f}};
  for (int kt = 0; kt < K1; kt += 16) {
    {
      const int row = t >> 2, k4 = (t & 3) * 4;
      const int gm = m0 + row;
      float4 v = make_float4(0.f, 0.f, 0.f, 0.f);
      if (gm < M) v = *(const float4*)(A1 + (size_t)gm * K1 + kt + k4);
      As[k4 + 0][row] = v.x; As[k4 + 1][row] = v.y;
      As[k4 + 2][row] = v.z; As[k4 + 3][row] = v.w;
      const int r = t >> 4, c4 = (t & 15) * 4;
      *(float4*)&Bs[r][c4] = *(const float4*)(B1 + (size_t)(kt + r) * Nn + n0 + c4);
    }
    __syncthreads();
    #pragma unroll
    for (int kk = 0; kk < 16; ++kk) {
      const float4 a = *(const float4*)&As[kk][ty * 4];
      const float4 b = *(const float4*)&Bs[kk][tx * 4];
      acc[0][0] += a.x * b.x; acc[0][1] += a.x * b.y; acc[0][2] += a.x * b.z; acc[0][3] += a.x * b.w;
      acc[1][0] += a.y * b.x; acc[1][1] += a.y * b.y; acc[1][2] += a.y * b.z; acc[1][3] += a.y * b.w;
      acc[2][0] += a.z * b.x; acc[2][1] += a.z * b.y; acc[2][2] += a.z * b.z; acc[2][3] += a.z * b.w;
      acc[3][0] += a.w * b.x; acc[3][1] += a.w * b.y; acc[3][2] += a.w * b.z; acc[3][3] += a.w * b.w;
    }
    __syncthreads();
  }
  float4 bv = make_float4(0.f, 0.f, 0.f, 0.f);
  if (bias) bv = *(const float4*)(bias + n0 + tx * 4);
  #pragma unroll
  for (int i = 0; i < 4; ++i) {
    const int gm = m0 + ty * 4 + i;
    if (gm >= M) continue;
    float4 o;
    o.x = acc[i][0] + bv.x; o.y = acc[i][1] + bv.y;
    o.z = acc[i][2] + bv.z; o.w = acc[i][3] + bv.w;
    *(float4*)(C + (size_t)gm * Nn + n0 + tx * 4) = o;
  }
}

// ---------------------------------------------------------------- sgemm, P/Q fused over z
__global__ __launch_bounds__(256) void sgemm2_k(
    const float* __restrict__ A1, int K1,
    const float* __restrict__ B1a, const float* __restrict__ B1b,
    const float* __restrict__ A2, int K2,
    const float* __restrict__ B2a, const float* __restrict__ B2b,
    const float* __restrict__ bias,
    float* __restrict__ Ca, float* __restrict__ Cb, int M, int Nn)
{
  __shared__ float As[16][68];
  __shared__ float Bs[16][64];
  const int z = blockIdx.z;
  const float* B1 = z ? B1b : B1a;
  const float* B2 = z ? B2b : B2a;
  float* C = z ? Cb : Ca;
  const float* bs = z ? nullptr : bias;
  const int t = threadIdx.x;
  const int m0 = blockIdx.y * 64, n0 = blockIdx.x * 64;
  const int tx = t & 15, ty = t >> 4;
  float acc[4][4] = {{0.f}};
  for (int pass = 0; pass < 2; ++pass) {
    const float* A = pass ? A2 : A1;
    const float* B = pass ? B2 : B1;
    const int K = pass ? K2 : K1;
    if (A == nullptr) continue;
    for (int kt = 0; kt < K; kt += 16) {
      {
        const int row = t >> 2, k4 = (t & 3) * 4;
        const int gm = m0 + row;
        float4 v = make_float4(0.f, 0.f, 0.f, 0.f);
        if (gm < M) v = *(const float4*)(A + (size_t)gm * K + kt + k4);
        As[k4 + 0][row] = v.x; As[k4 + 1][row] = v.y;
        As[k4 + 2][row] = v.z; As[k4 + 3][row] = v.w;
        const int r = t >> 4, c4 = (t & 15) * 4;
        *(float4*)&Bs[r][c4] = *(const float4*)(B + (size_t)(kt + r) * Nn + n0 + c4);
      }
      __syncthreads();
      #pragma unroll
      for (int kk = 0; kk < 16; ++kk) {
        const float4 a = *(const float4*)&As[kk][ty * 4];
        const float4 b = *(const float4*)&Bs[kk][tx * 4];
        acc[0][0] += a.x * b.x; acc[0][1] += a.x * b.y; acc[0][2] += a.x * b.z; acc[0][3] += a.x * b.w;
        acc[1][0] += a.y * b.x; acc[1][1] += a.y * b.y; acc[1][2] += a.y * b.z; acc[1][3] += a.y * b.w;
        acc[2][0] += a.z * b.x; acc[2][1] += a.z * b.y; acc[2][2] += a.z * b.z; acc[2][3] += a.z * b.w;
        acc[3][0] += a.w * b.x; acc[3][1] += a.w * b.y; acc[3][2] += a.w * b.z; acc[3][3] += a.w * b.w;
      }
      __syncthreads();
    }
  }
  float4 bv = make_float4(0.f, 0.f, 0.f, 0.f);
  if (bs) bv = *(const float4*)(bs + n0 + tx * 4);
  #pragma unroll
  for (int i = 0; i < 4; ++i) {
    const int gm = m0 + ty * 4 + i;
    if (gm >= M) continue;
    float4 o;
    o.x = acc[i][0] + bv.x; o.y = acc[i][1] + bv.y;
    o.z = acc[i][2] + bv.z; o.w = acc[i][3] + bv.w;
    *(float4*)(C + (size_t)gm * Nn + n0 + tx * 4) = o;
  }
}

#define FMA16(J) \
    acc[J][0] = fmaf(a.w, w3.x, fmaf(a.z, w2.x, fmaf(a.y, w1.x, fmaf(a.x, w0.x, acc[J][0])))); \
    acc[J][1] = fmaf(a.w, w3.y, fmaf(a.z, w2.y, fmaf(a.y, w1.y, fmaf(a.x, w0.y, acc[J][1])))); \
    acc[J][2] = fmaf(a.w, w3.z, fmaf(a.z, w2.z, fmaf(a.y, w1.z, fmaf(a.x, w0.z, acc[J][2])))); \
    acc[J][3] = fmaf(a.w, w3.w, fmaf(a.z, w2.w, fmaf(a.y, w1.w, fmaf(a.x, w0.w, acc[J][3]))));

// ---------------------------------------------------------------- edge conv
// m_e = ein_e @ We + P[src] + Q[dst]. Segmented dst-aggregation: per-block
// LDS accumulator; contained runs -> plain coalesced stores; only block-
// boundary runs use global atomics (atomics cost ~32B HBM/dword, measured).
// W streamed from L2 via register double-buffer (no Ws LDS, no extra barriers).
template<int BE, int NOUT, int ASTRIDE, bool RELUIN, bool GATHER, bool STOREM, bool WHEAD, bool SUB>
__global__ __launch_bounds__(256, 4) void econv_k(
    const float* __restrict__ ein0, const float* __restrict__ ein1,
    const float* __restrict__ We,
    const float* __restrict__ P, const float* __restrict__ Q,
    const int* __restrict__ ssrc, const int* __restrict__ sdst,
    const int* __restrict__ seid, const int* __restrict__ nKp,
    float* __restrict__ mout, float* __restrict__ xsum,
    const float* __restrict__ wvec, const float* __restrict__ wb,
    float* __restrict__ outw)
{
  constexpr int NC4 = NOUT / 4;     // 32 (NOUT=128) or 64 (NOUT=256)
  constexpr int TE  = 256 / NC4;    // strips per block
  constexpr int EPT = BE / TE;      // 8 edges per strip in both configs
  __shared__ float smem[8192];      // A-tile (BE*128) then agg (<=BE*NOUT=8192)
  __shared__ int darr[BE], slotOf[BE], firstE[BE];
  __shared__ int dcount_s, prevd_s, nextd_s;
  const int t = threadIdx.x;
  const int base = blockIdx.x * BE;
  int nvalid = BE;
  int Elim = N_EDGES;
  if constexpr (SUB) {
    const int nK = min(*nKp, EKCAP);
    if (base >= nK) return;
    nvalid = min(BE, nK - base);
    Elim = nK;
  }
  // ---- wave0: dst list, run-start scan -> slots ----
  if (t < 64) {
    if (t < BE) {
      int idx = base + t;
      if (SUB && idx >= Elim) idx = Elim - 1;
      darr[t] = sdst[idx];
    }
    if (t == 0) {
      prevd_s = (base > 0) ? sdst[base - 1] : -1;
      nextd_s = (base + BE < Elim) ? sdst[base + BE] : -1;
    }
    const int lane = t;
    const int myd = darr[(lane < BE) ? lane : (BE - 1)];
    int flag = 0;
    if (lane < BE) flag = (lane == 0) || (myd != darr[lane - 1]);
    int s = flag;
    #pragma unroll
    for (int o = 1; o < 64; o <<= 1) {
      const int v = __shfl_up(s, o);
      if (lane >= o) s += v;
    }
    if (lane < BE) {
      slotOf[lane] = s - 1;
      if (flag) firstE[s - 1] = lane;
    }
    if (lane == BE - 1) dcount_s = s;
  }
  const int tx = t % NC4, te = t / NC4;
  const int e0 = te * EPT;
  float4 acc[EPT];
  #pragma unroll
  for (int j = 0; j < EPT; ++j) acc[j] = make_float4(0.f, 0.f, 0.f, 0.f);
  const int nbuf = (ein1 != nullptr) ? 2 : 1;
  for (int buf = 0; buf < nbuf; ++buf) {
    const float* ein = buf ? ein1 : ein0;
    __syncthreads();
    #pragma unroll
    for (int i = t; i < BE * 32; i += 256) {
      const int e = i >> 5, k4 = (i & 31) * 4;
      const int g = base + e;
      const size_t row = GATHER ? (size_t)seid[g] : (size_t)g;
      float4 v = *(const float4*)(ein + row * ASTRIDE + k4);
      if (RELUIN) { v.x = frelu(v.x); v.y = frelu(v.y); v.z = frelu(v.z); v.w = frelu(v.w); }
      *(float4*)&smem[e * 128 + k4] = v;
    }
    __syncthreads();
    const float* Wb = We + (size_t)buf * 128 * NOUT + tx * 4;
    float4 wc0 = *(const float4*)(Wb + 0 * NOUT);
    float4 wc1 = *(const float4*)(Wb + 1 * NOUT);
    float4 wc2 = *(const float4*)(Wb + 2 * NOUT);
    float4 wc3 = *(const float4*)(Wb + 3 * NOUT);
    for (int kg = 0; kg < 32; ++kg) {
      const int kn = (kg < 31) ? (kg + 1) : 31;
      const float* Wn = Wb + (size_t)kn * 4 * NOUT;
      const float4 wn0 = *(const float4*)(Wn);
      const float4 wn1 = *(const float4*)(Wn + NOUT);
      const float4 wn2 = *(const float4*)(Wn + 2 * NOUT);
      const float4 wn3 = *(const float4*)(Wn + 3 * NOUT);
      #pragma unroll
      for (int j = 0; j < EPT; ++j) {
        const float4 a = *(const float4*)&smem[(e0 + j) * 128 + kg * 4];
        acc[j] = fma4(a.x, wc0, acc[j]);
        acc[j] = fma4(a.y, wc1, acc[j]);
        acc[j] = fma4(a.z, wc2, acc[j]);
        acc[j] = fma4(a.w, wc3, acc[j]);
      }
      wc0 = wn0; wc1 = wn1; wc2 = wn2; wc3 = wn3;
    }
  }
  // ---- zero agg region (reuses A-tile space) ----
  __syncthreads();
  {
    const float4 z = make_float4(0.f, 0.f, 0.f, 0.f);
    for (int i = t * 4; i < BE * NOUT; i += 1024) *(float4*)&smem[i] = z;
  }
  __syncthreads();
  // ---- epilogue: m = acc + P[src] + Q[dst]; run-compressed flush to LDS ----
  {
    float4 wv = make_float4(0.f, 0.f, 0.f, 0.f);
    if constexpr (WHEAD) wv = *(const float4*)(wvec + tx * 4);
    int cur = darr[e0];
    int slotCur = slotOf[e0];
    float4 q = *(const float4*)(Q + (size_t)cur * NOUT + tx * 4);
    float4 r = make_float4(0.f, 0.f, 0.f, 0.f);
    #pragma unroll
    for (int j = 0; j < EPT; ++j) {
      const int le = e0 + j;
      const int d = darr[le];
      if (d != cur) {
        float* a = &smem[slotCur * NOUT + tx * 4];
        atomicAdd(a + 0, r.x); atomicAdd(a + 1, r.y);
        atomicAdd(a + 2, r.z); atomicAdd(a + 3, r.w);
        cur = d; slotCur = slotOf[le];
        q = *(const float4*)(Q + (size_t)d * NOUT + tx * 4);
        r = make_float4(0.f, 0.f, 0.f, 0.f);
      }
      if (!SUB || le < nvalid) {
        const int g = base + le;
        const int s = ssrc[g];
        const float4 p = *(const float4*)(P + (size_t)s * NOUT + tx * 4);
        float4 m;
        m.x = acc[j].x + p.x + q.x; m.y = acc[j].y + p.y + q.y;
        m.z = acc[j].z + p.z + q.z; m.w = acc[j].w + p.w + q.w;
        if constexpr (STOREM) {
          *(float4*)(mout + (size_t)g * 128 + tx * 4) = m;
        }
        if constexpr (WHEAD) {
          float wp = frelu(m.x) * wv.x + frelu(m.y) * wv.y + frelu(m.z) * wv.z + frelu(m.w) * wv.w;
          #pragma unroll
          for (int o = 16; o > 0; o >>= 1) wp += __shfl_down(wp, o);
          if (tx == 0) outw[seid[g]] = 1.f / (1.f + expf(-(wp + wb[0])));
        }
        r.x += m.x; r.y += m.y; r.z += m.z; r.w += m.w;
      }
    }
    float* a = &smem[slotCur * NOUT + tx * 4];
    atomicAdd(a + 0, r.x); atomicAdd(a + 1, r.y);
    atomicAdd(a + 2, r.z); atomicAdd(a + 3, r.w);
  }
  __syncthreads();
  // ---- writeout: contained slots = plain stores; boundary slots = atomics ----
  {
    const int dc = dcount_s;
    const int pd = prevd_s, nd = nextd_s;
    for (int i = t * 4; i < dc * NOUT; i += 1024) {
      const int sidx = i / NOUT, col = i - sidx * NOUT;
      const int d = darr[firstE[sidx]];
      const bool strad = (sidx == 0 && d == pd) || (sidx == dc - 1 && d == nd);
      const float4 v = *(const float4*)&smem[i];
      float* o = xsum + (size_t)d * NOUT + col;
      if (!strad) {
        *(float4*)o = v;
      } else {
        atomicAdd(o + 0, v.x); atomicAdd(o + 1, v.y);
        atomicAdd(o + 2, v.z); atomicAdd(o + 3, v.w);
      }
    }
  }
}

// ---------------------------------------------------------------- presub:
// recompute es1 for kept edges: es1_i = relu(relu(e3[cidx])@We + P[src]+Q[dst])
__global__ __launch_bounds__(256, 4) void presub_k(
    const float* __restrict__ e3buf, const float* __restrict__ We,
    const float* __restrict__ P, const float* __restrict__ Q,
    const int* __restrict__ csrc, const int* __restrict__ cdst,
    const int* __restrict__ cidx, const int* __restrict__ nKp,
    float* __restrict__ es1out)  // row stride 256
{
  constexpr int BE = 32;
  const int nK = min(*nKp, EKCAP);
  const int base = blockIdx.x * BE;
  if (base >= nK) return;
  __shared__ float As[BE * 128];
  __shared__ float Ws[16 * 256];
  const int t = threadIdx.x;
  const int tx = t & 63, te = t >> 6;
  const int e0 = te * 8;
  float acc[8][4];
  #pragma unroll
  for (int j = 0; j < 8; ++j) { acc[j][0] = 0.f; acc[j][1] = 0.f; acc[j][2] = 0.f; acc[j][3] = 0.f; }
  #pragma unroll
  for (int i = t; i < BE * 32; i += 256) {
    const int e = i >> 5, k4 = (i & 31) * 4;
    const int g = base + e;
    const size_t row = (g < nK) ? (size_t)cidx[g] : 0;
    float4 v = *(const float4*)(e3buf + row * 128 + k4);
    v.x = frelu(v.x); v.y = frelu(v.y); v.z = frelu(v.z); v.w = frelu(v.w);
    *(float4*)&As[e * 128 + k4] = v;
  }
  for (int chunk = 0; chunk < 8; ++chunk) {
    __syncthreads();
    #pragma unroll
    for (int i = t; i < 16 * 64; i += 256) {
      const int r = i >> 6, c4 = (i & 63) * 4;
      *(float4*)&Ws[r * 256 + c4] = *(const float4*)(We + (size_t)(chunk * 16 + r) * 256 + c4);
    }
    __syncthreads();
    #pragma unroll
    for (int kk = 0; kk < 16; kk += 4) {
      const float4 w0 = *(const float4*)&Ws[(kk + 0) * 256 + tx * 4];
      const float4 w1 = *(const float4*)&Ws[(kk + 1) * 256 + tx * 4];
      const float4 w2 = *(const float4*)&Ws[(kk + 2) * 256 + tx * 4];
      const float4 w3 = *(const float4*)&Ws[(kk + 3) * 256 + tx * 4];
      #pragma unroll
      for (int j = 0; j < 8; ++j) {
        const float4 a = *(const float4*)&As[(e0 + j) * 128 + chunk * 16 + kk];
        FMA16(j)
      }
    }
  }
  #pragma unroll
  for (int j = 0; j < 8; ++j) {
    const int g = base + e0 + j;
    if (g < nK) {
      const int s = csrc[g], d = cdst[g];
      const float4 p = *(const float4*)(P + (size_t)s * 256 + tx * 4);
      const float4 q = *(const float4*)(Q + (size_t)d * 256 + tx * 4);
      float4 o;
      o.x = frelu(acc[j][0] + p.x + q.x); o.y = frelu(acc[j][1] + p.y + q.y);
      o.z = frelu(acc[j][2] + p.z + q.z); o.w = frelu(acc[j][3] + p.w + q.w);
      *(float4*)(es1out + (size_t)g * 256 + tx * 4) = o;
    }
  }
}

// ---------------------------------------------------------------- small kernels
__global__ void hist_k(const int* __restrict__ dst, int* __restrict__ deg, int E){
  const int e = blockIdx.x * 256 + threadIdx.x;
  if (e < E) atomicAdd(&deg[dst[e]], 1);
}

__global__ __launch_bounds__(1024) void scan_deg_k(
    const int* __restrict__ deg, int* __restrict__ rowstart, int* __restrict__ cursor,
    float* __restrict__ recip, int n)
{
  __shared__ int sb[1024];
  __shared__ int carry;
  const int t = threadIdx.x;
  if (t == 0) carry = 0;
  __syncthreads();
  const int CH = (n + 1023) >> 10;
  for (int c = 0; c < CH; ++c) {
    const int i = c * 1024 + t;
    const int d = (i < n) ? deg[i] : 0;
    sb[t] = d;
    __syncthreads();
    for (int off = 1; off < 1024; off <<= 1) {
      const int v = (t >= off) ? sb[t - off] : 0;
      __syncthreads();
      sb[t] += v;
      __syncthreads();
    }
    const int excl = sb[t] - d;
    const int tot = sb[1023];
    if (i < n) {
      const int rs = carry + excl;
      rowstart[i] = rs; cursor[i] = rs;
      recip[i] = 1.0f / (float)max(d, 1);
    }
    __syncthreads();
    if (t == 0) carry += tot;
    __syncthreads();
  }
  if (t == 0) rowstart[n] = carry;
}

__global__ void scatter_k(const int* __restrict__ src, const int* __restrict__ dst,
                          int* __restrict__ cursor, int* __restrict__ ssrc,
                          int* __restrict__ sdst, int* __restrict__ seid, int E){
  const int e = blockIdx.x * 256 + threadIdx.x;
  if (e < E) {
    const int d = dst[e];
    const int pos = atomicAdd(&cursor[d], 1);
    ssrc[pos] = src[e]; sdst[pos] = d; seid[pos] = e;
  }
}

__global__ void meanrelu_k(const float* __restrict__ xsum, const float* __restrict__ recip,
                           float* __restrict__ out, int total, int shift){
  const int i = blockIdx.x * 256 + threadIdx.x;
  if (i < total) out[i] = frelu(xsum[i] * recip[i >> shift]);
}

__global__ void h_k(const float* __restrict__ xs1, const float* __restrict__ Wg,
                    float* __restrict__ h, int n){
  const int node = blockIdx.x * 4 + (threadIdx.x >> 6);
  const int lane = threadIdx.x & 63;
  if (node >= n) return;
  const float4 x = *(const float4*)(xs1 + (size_t)node * 256 + lane * 4);
  const float4 w = *(const float4*)(Wg + lane * 4);
  float v = x.x * w.x + x.y * w.y + x.z * w.z + x.w * w.w;
  v = wsum(v);
  if (lane == 0) h[node] = v;
}

__global__ void att_k(const float* __restrict__ h, const int* __restrict__ rowstart,
                      const int* __restrict__ ssrc, const float* __restrict__ asp,
                      const float* __restrict__ adp, float* __restrict__ score, int n){
  const int node = blockIdx.x * 4 + (threadIdx.x >> 6);
  const int lane = threadIdx.x & 63;
  if (node >= n) return;
  const float a_s = asp[0], a_d = adp[0];
  const float hv = h[node];
  const int s0 = rowstart[node], s1 = rowstart[node + 1];
  const float selfea = fleaky(hv * (a_s + a_d));
  float mx = selfea;
  for (int i = s0 + lane; i < s1; i += 64) {
    const float hs = h[ssrc[i]];
    mx = fmaxf(mx, fleaky(hs * a_s + hv * a_d));
  }
  mx = wmaxr(mx);
  mx = __shfl(mx, 0);
  float den = 0.f, num = 0.f;
  if (lane == 0) { const float ez = expf(selfea - mx); den = ez; num = ez * hv; }
  for (int i = s0 + lane; i < s1; i += 64) {
    const float hs = h[ssrc[i]];
    const float ez = expf(fleaky(hs * a_s + hv * a_d) - mx);
    den += ez; num += ez * hs;
  }
  den = wsum(den); num = wsum(num);
  if (lane == 0) score[node] = num / den;
}

__device__ __forceinline__ unsigned keymap(float s){
  unsigned u = __float_as_uint(s);
  return (u & 0x80000000u) ? ~u : (u | 0x80000000u);
}

__global__ __launch_bounds__(1024) void topk_k(const float* __restrict__ score,
                                               int* __restrict__ kept,
                                               float* __restrict__ tfac, int n, int k)
{
  const int t = threadIdx.x;
  constexpr int CH = 20;  // covers n <= 20480
  unsigned key[CH];
  float sc[CH];
  #pragma unroll
  for (int c = 0; c < CH; ++c) {
    const int i = c * 1024 + t;
    if (i < n) { const float s = score[i]; sc[c] = s; key[c] = keymap(s); }
    else       { sc[c] = 0.f; key[c] = 0u; }
  }
  __shared__ int cnt;
  __shared__ int sb[1024];
  __shared__ int carry_eq;
  unsigned vstar = 0u;
  for (int b = 31; b >= 0; --b) {
    const unsigned cand = vstar | (1u << b);
    if (t == 0) cnt = 0;
    __syncthreads();
    int local = 0;
    #pragma unroll
    for (int c = 0; c < CH; ++c) local += (key[c] >= cand) ? 1 : 0;
    local = wsumi(local);
    if ((t & 63) == 0) atomicAdd(&cnt, local);
    __syncthreads();
    if (cnt >= k) vstar = cand;
    __syncthreads();
  }
  if (t == 0) cnt = 0;
  __syncthreads();
  {
    int local = 0;
    #pragma unroll
    for (int c = 0; c < CH; ++c) local += (key[c] > vstar) ? 1 : 0;
    local = wsumi(local);
    if ((t & 63) == 0) atomicAdd(&cnt, local);
  }
  __syncthreads();
  const int need = k - cnt;  // ties kept by lowest index
  if (t == 0) carry_eq = 0;
  __syncthreads();
  for (int c = 0; c < CH; ++c) {
    const int i = c * 1024 + t;
    const int flag = (i < n && key[c] == vstar) ? 1 : 0;
    sb[t] = flag;
    __syncthreads();
    for (int off = 1; off < 1024; off <<= 1) {
      const int v = (t >= off) ? sb[t - off] : 0;
      __syncthreads();
      sb[t] += v;
      __syncthreads();
    }
    const int rank = sb[t] - flag;
    const int tot = sb[1023];
    if (i < n) {
      const bool kp = (key[c] > vstar) || (flag && (carry_eq + rank) < need);
      kept[i] = kp ? 1 : 0;
      tfac[i] = kp ? tanhf(sc[c]) : 0.f;
    }
    __syncthreads();
    if (t == 0) carry_eq += tot;
    __syncthreads();
  }
}

__global__ void xpip_k(float* __restrict__ xs1, const float* __restrict__ tf, int total){
  const int i = blockIdx.x * 256 + threadIdx.x;
  if (i < total) xs1[i] *= tf[i >> 8];
}

__global__ __launch_bounds__(256) void flagsum_k(const int* __restrict__ kept,
    const int* __restrict__ ssrc, const int* __restrict__ sdst,
    int* __restrict__ bsum, int E){
  const int t = threadIdx.x;
  const int base = blockIdx.x * 1024;
  int loc = 0;
  #pragma unroll
  for (int j = 0; j < 4; ++j) {
    const int e = base + t * 4 + j;
    if (e < E) loc += kept[ssrc[e]] & kept[sdst[e]];
  }
  loc = wsumi(loc);
  __shared__ int wsh[4];
  if ((t & 63) == 0) wsh[t >> 6] = loc;
  __syncthreads();
  if (t == 0) bsum[blockIdx.x] = wsh[0] + wsh[1] + wsh[2] + wsh[3];
}

__global__ __launch_bounds__(512) void scanb_k(int* __restrict__ bsum, int nb, int* __restrict__ Ek){
  __shared__ int sb[512];
  const int t = threadIdx.x;
  const int v = (t < nb) ? bsum[t] : 0;
  sb[t] = v;
  __syncthreads();
  for (int off = 1; off < 512; off <<= 1) {
    const int u = (t >= off) ? sb[t - off] : 0;
    __syncthreads();
    sb[t] += u;
    __syncthreads();
  }
  if (t < nb) bsum[t] = sb[t] - v;   // exclusive
  if (t == 511) *Ek = sb[511];
}

__global__ __launch_bounds__(256) void compact_k(const int* __restrict__ kept,
    const int* __restrict__ ssrc, const int* __restrict__ sdst,
    const int* __restrict__ bsum, int* __restrict__ csrc, int* __restrict__ cdst,
    int* __restrict__ cidx, int* __restrict__ cntk, int E){
  const int t = threadIdx.x;
  const int base = blockIdx.x * 1024;
  int f[4]; int s = 0;
  #pragma unroll
  for (int j = 0; j < 4; ++j) {
    const int e = base + t * 4 + j;
    f[j] = (e < E) ? (kept[ssrc[e]] & kept[sdst[e]]) : 0;
    s += f[j];
  }
  __shared__ int sb[256];
  sb[t] = s;
  __syncthreads();
  for (int off = 1; off < 256; off <<= 1) {
    const int u = (t >= off) ? sb[t - off] : 0;
    __syncthreads();
    sb[t] += u;
    __syncthreads();
  }
  int pos = bsum[blockIdx.x] + sb[t] - s;
  #pragma unroll
  for (int j = 0; j < 4; ++j) {
    if (f[j]) {
      const int e = base + t * 4 + j;
      csrc[pos] = ssrc[e]; cdst[pos] = sdst[e]; cidx[pos] = e;
      atomicAdd(&cntk[sdst[e]], 1);
      ++pos;
    }
  }
}

__global__ void submerge_k(const float* __restrict__ x3, const float* __restrict__ xsum,
                           const int* __restrict__ cntk, const int* __restrict__ kept,
                           float* __restrict__ x32, int total){
  const int i = blockIdx.x * 256 + threadIdx.x;
  if (i >= total) return;
  const int v = i >> 7;
  float add = 0.f;
  if (kept[v]) {
    float c = (float)cntk[v];
    c = c > 0.f ? c : 1.f;
    add = frelu(xsum[i] / c);
  }
  x32[i] = x3[i] + add;
}

__global__ void fnode_k(const float* __restrict__ xsum, const float* __restrict__ recip,
                        const float* __restrict__ Wl1, const float* __restrict__ bl1,
                        float* __restrict__ out, int n){
  const int node = blockIdx.x * 4 + (threadIdx.x >> 6);
  const int lane = threadIdx.x & 63;
  if (node >= n) return;
  const float rc = recip[node];
  const float2 xv = *(const float2*)(xsum + (size_t)node * 128 + lane * 2);
  const float2 wv = *(const float2*)(Wl1 + lane * 2);
  float v = frelu(xv.x * rc) * wv.x + frelu(xv.y * rc) * wv.y;
  v = wsum(v);
  if (lane == 0) out[node] = 1.f / (1.f + expf(-(v + bl1[0])));
}

// ---------------------------------------------------------------- launch
extern "C" void kernel_launch(void* const* d_in, const int* in_sizes, int n_in,
                              void* d_out, int out_size, void* d_ws, size_t ws_size,
                              hipStream_t stream)
{
  const int N = N_NODES, E = N_EDGES;
  const float* node_feat = (const float*)d_in[0];
  const float* edge_feat = (const float*)d_in[1];
  const int*   eidx      = (const int*)d_in[2];
  const float* W_red = (const float*)d_in[3];  const float* b_red = (const float*)d_in[4];
  const float* W1 = (const float*)d_in[5];   const float* b1 = (const float*)d_in[6];
  const float* W2 = (const float*)d_in[7];   const float* b2 = (const float*)d_in[8];
  const float* W3 = (const float*)d_in[9];   const float* b3 = (const float*)d_in[10];
  const float* Wpre = (const float*)d_in[11]; const float* bpre = (const float*)d_in[12];
  const float* Wsub = (const float*)d_in[13]; const float* bsub = (const float*)d_in[14];
  const float* W4 = (const float*)d_in[15];  const float* b4 = (const float*)d_in[16];
  const float* Wg = (const float*)d_in[17];
  const float* a_s = (const float*)d_in[18]; const float* a_d = (const float*)d_in[19];
  const float* Wl1 = (const float*)d_in[20]; const float* bl1 = (const float*)d_in[21];
  const float* Ww = (const float*)d_in[22];  const float* bw = (const float*)d_in[23];
  float* out_x = (float*)d_out;
  float* out_w = out_x + N;

  char* wsb = (char*)d_ws;
  size_t off = 0;
  auto alloc = [&](size_t bytes) -> void* {
    void* p = wsb + off;
    off = (off + bytes + 255) & ~(size_t)255;
    return p;
  };
  float* u1   = (float*)alloc((size_t)E * 128 * 4);   // e1 -> e3a -> kept-es1(256-stride)
  float* u2   = (float*)alloc((size_t)E * 128 * 4);   // e2 -> e3
  float* n1   = (float*)alloc((size_t)N * 128 * 4);   // x0 -> x3a -> Psub -> x32
  float* n2   = (float*)alloc((size_t)N * 128 * 4);   // x1 -> x3
  float* n3   = (float*)alloc((size_t)N * 128 * 4);   // x2 -> Qsub
  float* xs1  = (float*)alloc((size_t)N * 256 * 4);   // xs1 -> xp (in place)
  float* P    = (float*)alloc((size_t)N * 256 * 4);
  float* Qb   = (float*)alloc((size_t)N * 256 * 4);
  float* xsum = (float*)alloc((size_t)N * 256 * 4);
  int* ssrc = (int*)alloc((size_t)E * 4);
  int* sdst = (int*)alloc((size_t)E * 4);
  int* seid = (int*)alloc((size_t)E * 4);
  int* csrc = (int*)alloc((size_t)E * 4);
  int* cdst = (int*)alloc((size_t)E * 4);
  int* cidx = (int*)alloc((size_t)E * 4);
  int* deg     = (int*)alloc((size_t)N * 4);
  int* cursor  = (int*)alloc((size_t)N * 4);
  int* rowstart= (int*)alloc((size_t)(N + 1) * 4);
  int* kept    = (int*)alloc((size_t)N * 4);
  int* cntk    = (int*)alloc((size_t)N * 4);
  float* recip = (float*)alloc((size_t)N * 4);
  float* hbuf  = (float*)alloc((size_t)N * 4);
  float* score = (float*)alloc((size_t)N * 4);
  float* tfac  = (float*)alloc((size_t)N * 4);
  int* bsum    = (int*)alloc(1024 * 4);
  int* Ek      = (int*)alloc(256);
  (void)ws_size; (void)in_sizes; (void)n_in; (void)out_size;

  const dim3 g128z(2, (N + 63) / 64, 2), g256z(4, (N + 63) / 64, 2);
  const dim3 g128(2, (N + 63) / 64);
  const int nbFS = (E + 1023) / 1024;
  #define NILS nullptr, nullptr, nullptr

  // ---- sort edges by dst (counting sort) ----
  hipMemsetAsync(deg, 0, (size_t)N * 4, stream);
  hist_k<<<(E + 255) / 256, 256, 0, stream>>>(eidx + E, deg, E);
  scan_deg_k<<<1, 1024, 0, stream>>>(deg, rowstart, cursor, recip, N);
  scatter_k<<<(E + 255) / 256, 256, 0, stream>>>(eidx, eidx + E, cursor, ssrc, sdst, seid, E);

  // ---- x0 = node_feat @ W_red + b_red -> n1 ----
  sgemm_k<<<g128, 256, 0, stream>>>(node_feat, 256, W_red, b_red, n1, N, 128);

  // ---- conv1: e in edge_feat(gather), out u1; x1 -> n2 ----
  sgemm2_k<<<g128z, 256, 0, stream>>>(n1, 128, W1, W1 + 128 * 128,
                                      nullptr, 0, nullptr, nullptr, b1, P, Qb, N, 128);
  hipMemsetAsync(xsum, 0, (size_t)N * 128 * 4, stream);
  econv_k<64, 128, 128, false, true, true, false, false><<<E / 64, 256, 0, stream>>>(
      edge_feat, nullptr, W1 + 256 * 128, P, Qb, ssrc, sdst, seid, nullptr, u1, xsum, NILS);
  meanrelu_k<<<(N * 128) / 256, 256, 0, stream>>>(xsum, recip, n2, N * 128, 7);

  // ---- conv2: in u1(e1), out u2; x2 -> n3 ----
  sgemm2_k<<<g128z, 256, 0, stream>>>(n2, 128, W2, W2 + 128 * 128,
                                      nullptr, 0, nullptr, nullptr, b2, P, Qb, N, 128);
  hipMemsetAsync(xsum, 0, (size_t)N * 128 * 4, stream);
  econv_k<64, 128, 128, true, false, true, false, false><<<E / 64, 256, 0, stream>>>(
      u1, nullptr, W2 + 256 * 128, P, Qb, ssrc, sdst, seid, nullptr, u2, xsum, NILS);
  meanrelu_k<<<(N * 128) / 256, 256, 0, stream>>>(xsum, recip, n3, N * 128, 7);

  // ---- conv3 (first): ein=[e2,e1]; e3a overwrites u1 in place; x3a -> n1 ----
  sgemm2_k<<<g128z, 256, 0, stream>>>(n3, 128, W3, W3 + 256 * 128,
                                      n2, 128, W3 + 128 * 128, W3 + 384 * 128, b3, P, Qb, N, 128);
  hipMemsetAsync(xsum, 0, (size_t)N * 128 * 4, stream);
  econv_k<64, 128, 128, true, false, true, false, false><<<E / 64, 256, 0, stream>>>(
      u2, u1, W3 + 512 * 128, P, Qb, ssrc, sdst, seid, nullptr, u1, xsum, NILS);
  meanrelu_k<<<(N * 128) / 256, 256, 0, stream>>>(xsum, recip, n1, N * 128, 7);

  // ---- conv3 (second, shared W3): ein=[e3a,e2]; e3 overwrites u2; x3 -> n2 ----
  sgemm2_k<<<g128z, 256, 0, stream>>>(n1, 128, W3, W3 + 256 * 128,
                                      n3, 128, W3 + 128 * 128, W3 + 384 * 128, b3, P, Qb, N, 128);
  hipMemsetAsync(xsum, 0, (size_t)N * 128 * 4, stream);
  econv_k<64, 128, 128, true, false, true, false, false><<<E / 64, 256, 0, stream>>>(
      u1, u2, W3 + 512 * 128, P, Qb, ssrc, sdst, seid, nullptr, u2, xsum, NILS);
  meanrelu_k<<<(N * 128) / 256, 256, 0, stream>>>(xsum, recip, n2, N * 128, 7);

  // ---- pre conv (NOUT=256), aggregate only; xs1 ----
  sgemm2_k<<<g256z, 256, 0, stream>>>(n2, 128, Wpre, Wpre + 128 * 256,
                                      nullptr, 0, nullptr, nullptr, bpre, P, Qb, N, 256);
  hipMemsetAsync(xsum, 0, (size_t)N * 256 * 4, stream);
  econv_k<32, 256, 128, true, false, false, false, false><<<E / 32, 256, 0, stream>>>(
      u2, nullptr, Wpre + 256 * 256, P, Qb, ssrc, sdst, seid, nullptr, nullptr, xsum, NILS);
  meanrelu_k<<<(N * 256) / 256, 256, 0, stream>>>(xsum, recip, xs1, N * 256, 8);

  // ---- SAGPool scorer + top-k; xp in-place over xs1 ----
  h_k<<<(N + 3) / 4, 256, 0, stream>>>(xs1, Wg, hbuf, N);
  att_k<<<(N + 3) / 4, 256, 0, stream>>>(hbuf, rowstart, ssrc, a_s, a_d, score, N);
  topk_k<<<1, 1024, 0, stream>>>(score, kept, tfac, N, N / 2);
  xpip_k<<<(N * 256) / 256, 256, 0, stream>>>(xs1, tfac, N * 256);

  // ---- compact kept edges ----
  hipMemsetAsync(cntk, 0, (size_t)N * 4, stream);
  flagsum_k<<<nbFS, 256, 0, stream>>>(kept, ssrc, sdst, bsum, E);
  scanb_k<<<1, 512, 0, stream>>>(bsum, nbFS, Ek);
  compact_k<<<nbFS, 256, 0, stream>>>(kept, ssrc, sdst, bsum, csrc, cdst, cidx, cntk, E);

  // ---- sub conv: Psub -> n1, Qsub -> n3 ----
  sgemm2_k<<<g128z, 256, 0, stream>>>(xs1, 256, Wsub, Wsub + 256 * 128,
                                      nullptr, 0, nullptr, nullptr, bsub, n1, n3, N, 128);
  presub_k<<<(EKCAP + 31) / 32, 256, 0, stream>>>(
      u2, Wpre + 256 * 256, P, Qb, csrc, cdst, cidx, Ek, u1);
  hipMemsetAsync(xsum, 0, (size_t)N * 128 * 4, stream);
  econv_k<64, 128, 256, false, false, false, false, true><<<(EKCAP + 63) / 64, 256, 0, stream>>>(
      u1, u1 + 128, Wsub + 512 * 128, n1, n3, csrc, cdst, nullptr, Ek, nullptr, xsum, NILS);
  submerge_k<<<(N * 128) / 256, 256, 0, stream>>>(n2, xsum, cntk, kept, n1, N * 128);

  // ---- conv4: ein=e3(u2); fused w-head, no m store ----
  sgemm2_k<<<g128z, 256, 0, stream>>>(n1, 128, W4, W4 + 256 * 128,
                                      n2, 128, W4 + 128 * 128, W4 + 384 * 128, b4, P, Qb, N, 128);
  hipMemsetAsync(xsum, 0, (size_t)N * 128 * 4, stream);
  econv_k<64, 128, 128, true, false, false, true, false><<<E / 64, 256, 0, stream>>>(
      u2, nullptr, W4 + 512 * 128, P, Qb, ssrc, sdst, seid, nullptr, nullptr, xsum, Ww, bw, out_w);

  // ---- node head ----
  fnode_k<<<(N + 3) / 4, 256, 0, stream>>>(xsum, recip, Wl1, bl1, out_x, N);
  #undef NILS
}

// Round 5
// 2087.396 us; speedup vs baseline: 1.3320x; 1.2419x over previous
//
#include <hip/hip_runtime.h>
#include <cstdint>
#include <cstddef>

#define N_NODES 20000
#define N_EDGES 320000
#define EKCAP   (N_EDGES / 2)

typedef __attribute__((ext_vector_type(8))) _Float16 half8;
typedef __attribute__((ext_vector_type(4))) _Float16 half4;
typedef __attribute__((ext_vector_type(4))) float f32x4;

__device__ __forceinline__ float frelu(float x){ return x > 0.f ? x : 0.f; }
__device__ __forceinline__ float fleaky(float x){ return x > 0.f ? x : 0.2f*x; }

__device__ __forceinline__ float wsum(float v){
  #pragma unroll
  for (int o = 32; o > 0; o >>= 1) v += __shfl_down(v, o);
  return v;
}
__device__ __forceinline__ float wmaxr(float v){
  #pragma unroll
  for (int o = 32; o > 0; o >>= 1) v = fmaxf(v, __shfl_down(v, o));
  return v;
}
__device__ __forceinline__ int wsumi(int v){
  #pragma unroll
  for (int o = 32; o > 0; o >>= 1) v += __shfl_down(v, o);
  return v;
}

// ---------------------------------------------------------------- sgemm (single out)
__global__ __launch_bounds__(256) void sgemm_k(
    const float* __restrict__ A1, int K1, const float* __restrict__ B1,
    const float* __restrict__ bias, float* __restrict__ C, int M, int Nn)
{
  __shared__ float As[16][68];
  __shared__ float Bs[16][64];
  const int t = threadIdx.x;
  const int m0 = blockIdx.y * 64, n0 = blockIdx.x * 64;
  const int tx = t & 15, ty = t >> 4;
  float acc[4][4] = {{0.f}};
  for (int kt = 0; kt < K1; kt += 16) {
    {
      const int row = t >> 2, k4 = (t & 3) * 4;
      const int gm = m0 + row;
      float4 v = make_float4(0.f, 0.f, 0.f, 0.f);
      if (gm < M) v = *(const float4*)(A1 + (size_t)gm * K1 + kt + k4);
      As[k4 + 0][row] = v.x; As[k4 + 1][row] = v.y;
      As[k4 + 2][row] = v.z; As[k4 + 3][row] = v.w;
      const int r = t >> 4, c4 = (t & 15) * 4;
      *(float4*)&Bs[r][c4] = *(const float4*)(B1 + (size_t)(kt + r) * Nn + n0 + c4);
    }
    __syncthreads();
    #pragma unroll
    for (int kk = 0; kk < 16; ++kk) {
      const float4 a = *(const float4*)&As[kk][ty * 4];
      const float4 b = *(const float4*)&Bs[kk][tx * 4];
      acc[0][0] += a.x * b.x; acc[0][1] += a.x * b.y; acc[0][2] += a.x * b.z; acc[0][3] += a.x * b.w;
      acc[1][0] += a.y * b.x; acc[1][1] += a.y * b.y; acc[1][2] += a.y * b.z; acc[1][3] += a.y * b.w;
      acc[2][0] += a.z * b.x; acc[2][1] += a.z * b.y; acc[2][2] += a.z * b.z; acc[2][3] += a.z * b.w;
      acc[3][0] += a.w * b.x; acc[3][1] += a.w * b.y; acc[3][2] += a.w * b.z; acc[3][3] += a.w * b.w;
    }
    __syncthreads();
  }
  float4 bv = make_float4(0.f, 0.f, 0.f, 0.f);
  if (bias) bv = *(const float4*)(bias + n0 + tx * 4);
  #pragma unroll
  for (int i = 0; i < 4; ++i) {
    const int gm = m0 + ty * 4 + i;
    if (gm >= M) continue;
    float4 o;
    o.x = acc[i][0] + bv.x; o.y = acc[i][1] + bv.y;
    o.z = acc[i][2] + bv.z; o.w = acc[i][3] + bv.w;
    *(float4*)(C + (size_t)gm * Nn + n0 + tx * 4) = o;
  }
}

// ---------------------------------------------------------------- sgemm, P/Q fused over z
__global__ __launch_bounds__(256) void sgemm2_k(
    const float* __restrict__ A1, int K1,
    const float* __restrict__ B1a, const float* __restrict__ B1b,
    const float* __restrict__ A2, int K2,
    const float* __restrict__ B2a, const float* __restrict__ B2b,
    const float* __restrict__ bias,
    float* __restrict__ Ca, float* __restrict__ Cb, int M, int Nn)
{
  __shared__ float As[16][68];
  __shared__ float Bs[16][64];
  const int z = blockIdx.z;
  const float* B1 = z ? B1b : B1a;
  const float* B2 = z ? B2b : B2a;
  float* C = z ? Cb : Ca;
  const float* bs = z ? nullptr : bias;
  const int t = threadIdx.x;
  const int m0 = blockIdx.y * 64, n0 = blockIdx.x * 64;
  const int tx = t & 15, ty = t >> 4;
  float acc[4][4] = {{0.f}};
  for (int pass = 0; pass < 2; ++pass) {
    const float* A = pass ? A2 : A1;
    const float* B = pass ? B2 : B1;
    const int K = pass ? K2 : K1;
    if (A == nullptr) continue;
    for (int kt = 0; kt < K; kt += 16) {
      {
        const int row = t >> 2, k4 = (t & 3) * 4;
        const int gm = m0 + row;
        float4 v = make_float4(0.f, 0.f, 0.f, 0.f);
        if (gm < M) v = *(const float4*)(A + (size_t)gm * K + kt + k4);
        As[k4 + 0][row] = v.x; As[k4 + 1][row] = v.y;
        As[k4 + 2][row] = v.z; As[k4 + 3][row] = v.w;
        const int r = t >> 4, c4 = (t & 15) * 4;
        *(float4*)&Bs[r][c4] = *(const float4*)(B + (size_t)(kt + r) * Nn + n0 + c4);
      }
      __syncthreads();
      #pragma unroll
      for (int kk = 0; kk < 16; ++kk) {
        const float4 a = *(const float4*)&As[kk][ty * 4];
        const float4 b = *(const float4*)&Bs[kk][tx * 4];
        acc[0][0] += a.x * b.x; acc[0][1] += a.x * b.y; acc[0][2] += a.x * b.z; acc[0][3] += a.x * b.w;
        acc[1][0] += a.y * b.x; acc[1][1] += a.y * b.y; acc[1][2] += a.y * b.z; acc[1][3] += a.y * b.w;
        acc[2][0] += a.z * b.x; acc[2][1] += a.z * b.y; acc[2][2] += a.z * b.z; acc[2][3] += a.z * b.w;
        acc[3][0] += a.w * b.x; acc[3][1] += a.w * b.y; acc[3][2] += a.w * b.z; acc[3][3] += a.w * b.w;
      }
      __syncthreads();
    }
  }
  float4 bv = make_float4(0.f, 0.f, 0.f, 0.f);
  if (bs) bv = *(const float4*)(bs + n0 + tx * 4);
  #pragma unroll
  for (int i = 0; i < 4; ++i) {
    const int gm = m0 + ty * 4 + i;
    if (gm >= M) continue;
    float4 o;
    o.x = acc[i][0] + bv.x; o.y = acc[i][1] + bv.y;
    o.z = acc[i][2] + bv.z; o.w = acc[i][3] + bv.w;
    *(float4*)(C + (size_t)gm * Nn + n0 + tx * 4) = o;
  }
}

// ---------------------------------------------------------------- weight split
// WTh/WTl[n*K + k] = fp16 split of We[k*NOUT + n]  (transposed, k-contiguous)
__global__ __launch_bounds__(256) void wsplit_k(
    const float* __restrict__ We, int K, int NOUT,
    _Float16* __restrict__ WTh, _Float16* __restrict__ WTl)
{
  const int id = blockIdx.x * 256 + threadIdx.x;
  if (id >= K * NOUT) return;
  const int k = id / NOUT, n = id - k * NOUT;
  const float v = We[id];
  const _Float16 h = (_Float16)v;
  WTh[(size_t)n * K + k] = h;
  WTl[(size_t)n * K + k] = (_Float16)(v - (float)h);
}

// ---------------------------------------------------------------- MFMA edge conv
// m_e = ein_e @ We + P[src] + Q[dst], NOUT=128 always. Edge GEMM via
// mfma_f32_16x16x32_f16 with 2-term fp16 split (hh+hl+lh, fp32 acc ~ fp32
// accuracy). A staged in LDS as hi/lo fp16 planes (stride 136, 2-way-free
// banks); B streamed from L2 (pre-split W^T [n][k]). C-frags round-trip via
// LDS m-buffer so the verified segmented-aggregation epilogue is reused:
// contained runs -> plain stores, boundary/overflow -> global atomics.
template<bool RELUIN, bool GATHER, bool STOREM, bool WHEAD, bool SUB, bool AGG>
__global__ __launch_bounds__(256, 3) void econv_m(
    const float* __restrict__ ein0, const float* __restrict__ ein1, int astride,
    const _Float16* __restrict__ WTh, const _Float16* __restrict__ WTl,
    const float* __restrict__ P, const float* __restrict__ Q, int pqs,
    const int* __restrict__ ssrc, const int* __restrict__ sdst,
    const int* __restrict__ gidx, const int* __restrict__ seid,
    const int* __restrict__ nKp,
    float* __restrict__ mout, int ms,
    float* __restrict__ xsum, int xss,
    const float* __restrict__ wvec, const float* __restrict__ wb,
    float* __restrict__ outw)
{
  __shared__ __align__(16) char uA[34816];          // A hi/lo planes, later m-buffer
  __shared__ __align__(16) float agg[16 * 132];
  __shared__ int darr[64], slotOf[64], firstE[64];
  __shared__ int dcount_s, prevd_s, nextd_s;
  _Float16* Ah = (_Float16*)uA;                     // [64][136]
  _Float16* Al = Ah + 64 * 136;
  float* mld = (float*)uA;                          // [64][132] (after GEMM)

  const int t = threadIdx.x;
  const int base = blockIdx.x * 64;
  const int nbuf = (ein1 != nullptr) ? 2 : 1;
  int nvalid = 64, Elim = N_EDGES;
  if constexpr (SUB) {
    const int nK = min(*nKp, EKCAP);
    if (base >= nK) return;
    nvalid = min(64, nK - base);
    Elim = nK;
  }
  // ---- wave0: dst run-scan -> slots (AGG only) ----
  if (AGG && t < 64) {
    {
      int idx = base + t;
      if (SUB && idx >= Elim) idx = Elim - 1;
      darr[t] = sdst[idx];
    }
    if (t == 0) {
      prevd_s = (base > 0) ? sdst[base - 1] : -1;
      nextd_s = (base + 64 < Elim) ? sdst[base + 64] : -1;
    }
    const int lane = t;
    const int myd = darr[lane];
    int flag = (lane == 0) || (myd != darr[lane - 1]);
    int s = flag;
    #pragma unroll
    for (int o = 1; o < 64; o <<= 1) {
      const int v = __shfl_up(s, o);
      if (lane >= o) s += v;
    }
    slotOf[lane] = s - 1;
    if (flag) firstE[s - 1] = lane;
    if (lane == 63) dcount_s = s;
  }
  // ---- GEMM: stage A (fp16 split) + MFMA, per 128-K buf ----
  const int lane = t & 63;
  const int wv64 = t >> 6;            // wave 0..3 -> cols [wv64*32, +32)
  const int m16 = lane & 15;
  const int q8  = (lane >> 4) * 8;
  const int Ktot = nbuf * 128;
  f32x4 acc[8];
  #pragma unroll
  for (int i = 0; i < 8; ++i) acc[i] = (f32x4)0.f;

  for (int buf = 0; buf < nbuf; ++buf) {
    const float* ein = buf ? ein1 : ein0;
    __syncthreads();
    #pragma unroll
    for (int i = t; i < 64 * 32; i += 256) {
      const int e = i >> 5, kg = (i & 31) * 4;
      const int g = base + e;
      size_t row;
      if (GATHER) row = (!SUB || g < Elim) ? (size_t)gidx[g] : 0;
      else        row = (size_t)g;
      float4 v = *(const float4*)(ein + row * astride + kg);
      if (RELUIN) { v.x = frelu(v.x); v.y = frelu(v.y); v.z = frelu(v.z); v.w = frelu(v.w); }
      half4 hv, lv;
      _Float16 h;
      h = (_Float16)v.x; hv[0] = h; lv[0] = (_Float16)(v.x - (float)h);
      h = (_Float16)v.y; hv[1] = h; lv[1] = (_Float16)(v.y - (float)h);
      h = (_Float16)v.z; hv[2] = h; lv[2] = (_Float16)(v.z - (float)h);
      h = (_Float16)v.w; hv[3] = h; lv[3] = (_Float16)(v.w - (float)h);
      *(half4*)&Ah[e * 136 + kg] = hv;
      *(half4*)&Al[e * 136 + kg] = lv;
    }
    __syncthreads();
    #pragma unroll
    for (int kk = 0; kk < 4; ++kk) {
      const int k0 = kk * 32 + q8;
      half8 a_h[4], a_l[4];
      #pragma unroll
      for (int mt = 0; mt < 4; ++mt) {
        const int m = mt * 16 + m16;
        a_h[mt] = *(const half8*)&Ah[m * 136 + k0];
        a_l[mt] = *(const half8*)&Al[m * 136 + k0];
      }
      #pragma unroll
      for (int nt = 0; nt < 2; ++nt) {
        const size_t boff = (size_t)(wv64 * 32 + nt * 16 + m16) * Ktot + buf * 128 + k0;
        const half8 b_h = *(const half8*)(WTh + boff);
        const half8 b_l = *(const half8*)(WTl + boff);
        #pragma unroll
        for (int mt = 0; mt < 4; ++mt) {
          f32x4 c = acc[mt * 2 + nt];
          c = __builtin_amdgcn_mfma_f32_16x16x32_f16(a_h[mt], b_h, c, 0, 0, 0);
          c = __builtin_amdgcn_mfma_f32_16x16x32_f16(a_h[mt], b_l, c, 0, 0, 0);
          c = __builtin_amdgcn_mfma_f32_16x16x32_f16(a_l[mt], b_h, c, 0, 0, 0);
          acc[mt * 2 + nt] = c;
        }
      }
    }
  }
  // ---- C-frags -> LDS m-buffer (C/D: col=lane&15, row=quad*4+reg) ----
  __syncthreads();
  {
    const int qrow = (lane >> 4) * 4;
    #pragma unroll
    for (int mt = 0; mt < 4; ++mt) {
      #pragma unroll
      for (int nt = 0; nt < 2; ++nt) {
        const int col = wv64 * 32 + nt * 16 + m16;
        const int row = mt * 16 + qrow;
        const f32x4 c = acc[mt * 2 + nt];
        mld[(row + 0) * 132 + col] = c[0];
        mld[(row + 1) * 132 + col] = c[1];
        mld[(row + 2) * 132 + col] = c[2];
        mld[(row + 3) * 132 + col] = c[3];
      }
    }
  }
  if constexpr (AGG) {
    for (int i = t; i < 16 * 132; i += 256) agg[i] = 0.f;
  }
  __syncthreads();
  // ---- epilogue ----
  const int tx = t & 31, te = t >> 5;
  const int e0 = te * 8;
  if constexpr (!AGG) {
    // presub path: store m only (per-edge Q, no aggregation)
    #pragma unroll
    for (int j = 0; j < 8; ++j) {
      const int le = e0 + j;
      if (le < nvalid) {
        const int g = base + le;
        const int s = ssrc[g], d = sdst[g];
        const float4 mm = *(const float4*)&mld[le * 132 + tx * 4];
        const float4 p = *(const float4*)(P + (size_t)s * pqs + tx * 4);
        const float4 q = *(const float4*)(Q + (size_t)d * pqs + tx * 4);
        float4 o;
        o.x = mm.x + p.x + q.x; o.y = mm.y + p.y + q.y;
        o.z = mm.z + p.z + q.z; o.w = mm.w + p.w + q.w;
        *(float4*)(mout + (size_t)g * ms + tx * 4) = o;
      }
    }
    return;
  } else {
    float4 wvv = make_float4(0.f, 0.f, 0.f, 0.f);
    if constexpr (WHEAD) wvv = *(const float4*)(wvec + tx * 4);
    int cur = darr[e0];
    int slotCur = slotOf[e0];
    float4 q = *(const float4*)(Q + (size_t)cur * pqs + tx * 4);
    float4 r = make_float4(0.f, 0.f, 0.f, 0.f);
    #pragma unroll
    for (int j = 0; j < 8; ++j) {
      const int le = e0 + j;
      const int d = darr[le];
      if (d != cur) {
        if (slotCur < 16) {
          float* a = &agg[slotCur * 132 + tx * 4];
          atomicAdd(a + 0, r.x); atomicAdd(a + 1, r.y);
          atomicAdd(a + 2, r.z); atomicAdd(a + 3, r.w);
        } else {
          float* o = xsum + (size_t)cur * xss + tx * 4;
          atomicAdd(o + 0, r.x); atomicAdd(o + 1, r.y);
          atomicAdd(o + 2, r.z); atomicAdd(o + 3, r.w);
        }
        cur = d; slotCur = slotOf[le];
        q = *(const float4*)(Q + (size_t)d * pqs + tx * 4);
        r = make_float4(0.f, 0.f, 0.f, 0.f);
      }
      if (!SUB || le < nvalid) {
        const int g = base + le;
        const int s = ssrc[g];
        const float4 mm = *(const float4*)&mld[le * 132 + tx * 4];
        const float4 p = *(const float4*)(P + (size_t)s * pqs + tx * 4);
        float4 m;
        m.x = mm.x + p.x + q.x; m.y = mm.y + p.y + q.y;
        m.z = mm.z + p.z + q.z; m.w = mm.w + p.w + q.w;
        if constexpr (STOREM) {
          *(float4*)(mout + (size_t)g * ms + tx * 4) = m;
        }
        if constexpr (WHEAD) {
          float wp = frelu(m.x) * wvv.x + frelu(m.y) * wvv.y + frelu(m.z) * wvv.z + frelu(m.w) * wvv.w;
          #pragma unroll
          for (int o = 16; o > 0; o >>= 1) wp += __shfl_down(wp, o);
          if (tx == 0) outw[seid[g]] = 1.f / (1.f + expf(-(wp + wb[0])));
        }
        r.x += m.x; r.y += m.y; r.z += m.z; r.w += m.w;
      }
    }
    if (slotCur < 16) {
      float* a = &agg[slotCur * 132 + tx * 4];
      atomicAdd(a + 0, r.x); atomicAdd(a + 1, r.y);
      atomicAdd(a + 2, r.z); atomicAdd(a + 3, r.w);
    } else {
      float* o = xsum + (size_t)cur * xss + tx * 4;
      atomicAdd(o + 0, r.x); atomicAdd(o + 1, r.y);
      atomicAdd(o + 2, r.z); atomicAdd(o + 3, r.w);
    }
    __syncthreads();
    // ---- writeout ----
    const int dc = dcount_s;
    const int dcl = min(dc, 16);
    const int pd = prevd_s, nd = nextd_s;
    for (int i = t * 4; i < dcl * 128; i += 1024) {
      const int slot = i >> 7, col = i & 127;
      const int d = darr[firstE[slot]];
      const bool strad = (slot == 0 && d == pd) || (slot == dc - 1 && d == nd);
      const float4 v = *(const float4*)&agg[slot * 132 + col];
      float* o = xsum + (size_t)d * xss + col;
      if (!strad) {
        *(float4*)o = v;
      } else {
        atomicAdd(o + 0, v.x); atomicAdd(o + 1, v.y);
        atomicAdd(o + 2, v.z); atomicAdd(o + 3, v.w);
      }
    }
  }
}

// ---------------------------------------------------------------- small kernels
__global__ void hist_k(const int* __restrict__ dst, int* __restrict__ deg, int E){
  const int e = blockIdx.x * 256 + threadIdx.x;
  if (e < E) atomicAdd(&deg[dst[e]], 1);
}

__global__ __launch_bounds__(1024) void scan_deg_k(
    const int* __restrict__ deg, int* __restrict__ rowstart, int* __restrict__ cursor,
    float* __restrict__ recip, int n)
{
  __shared__ int sb[1024];
  __shared__ int carry;
  const int t = threadIdx.x;
  if (t == 0) carry = 0;
  __syncthreads();
  const int CH = (n + 1023) >> 10;
  for (int c = 0; c < CH; ++c) {
    const int i = c * 1024 + t;
    const int d = (i < n) ? deg[i] : 0;
    sb[t] = d;
    __syncthreads();
    for (int off = 1; off < 1024; off <<= 1) {
      const int v = (t >= off) ? sb[t - off] : 0;
      __syncthreads();
      sb[t] += v;
      __syncthreads();
    }
    const int excl = sb[t] - d;
    const int tot = sb[1023];
    if (i < n) {
      const int rs = carry + excl;
      rowstart[i] = rs; cursor[i] = rs;
      recip[i] = 1.0f / (float)max(d, 1);
    }
    __syncthreads();
    if (t == 0) carry += tot;
    __syncthreads();
  }
  if (t == 0) rowstart[n] = carry;
}

__global__ void scatter_k(const int* __restrict__ src, const int* __restrict__ dst,
                          int* __restrict__ cursor, int* __restrict__ ssrc,
                          int* __restrict__ sdst, int* __restrict__ seid, int E){
  const int e = blockIdx.x * 256 + threadIdx.x;
  if (e < E) {
    const int d = dst[e];
    const int pos = atomicAdd(&cursor[d], 1);
    ssrc[pos] = src[e]; sdst[pos] = d; seid[pos] = e;
  }
}

__global__ void meanrelu_k(const float* __restrict__ xsum, const float* __restrict__ recip,
                           float* __restrict__ out, int total, int shift){
  const int i = blockIdx.x * 256 + threadIdx.x;
  if (i < total) out[i] = frelu(xsum[i] * recip[i >> shift]);
}

__global__ void h_k(const float* __restrict__ xs1, const float* __restrict__ Wg,
                    float* __restrict__ h, int n){
  const int node = blockIdx.x * 4 + (threadIdx.x >> 6);
  const int lane = threadIdx.x & 63;
  if (node >= n) return;
  const float4 x = *(const float4*)(xs1 + (size_t)node * 256 + lane * 4);
  const float4 w = *(const float4*)(Wg + lane * 4);
  float v = x.x * w.x + x.y * w.y + x.z * w.z + x.w * w.w;
  v = wsum(v);
  if (lane == 0) h[node] = v;
}

__global__ void att_k(const float* __restrict__ h, const int* __restrict__ rowstart,
                      const int* __restrict__ ssrc, const float* __restrict__ asp,
                      const float* __restrict__ adp, float* __restrict__ score, int n){
  const int node = blockIdx.x * 4 + (threadIdx.x >> 6);
  const int lane = threadIdx.x & 63;
  if (node >= n) return;
  const float a_s = asp[0], a_d = adp[0];
  const float hv = h[node];
  const int s0 = rowstart[node], s1 = rowstart[node + 1];
  const float selfea = fleaky(hv * (a_s + a_d));
  float mx = selfea;
  for (int i = s0 + lane; i < s1; i += 64) {
    const float hs = h[ssrc[i]];
    mx = fmaxf(mx, fleaky(hs * a_s + hv * a_d));
  }
  mx = wmaxr(mx);
  mx = __shfl(mx, 0);
  float den = 0.f, num = 0.f;
  if (lane == 0) { const float ez = expf(selfea - mx); den = ez; num = ez * hv; }
  for (int i = s0 + lane; i < s1; i += 64) {
    const float hs = h[ssrc[i]];
    const float ez = expf(fleaky(hs * a_s + hv * a_d) - mx);
    den += ez; num += ez * hs;
  }
  den = wsum(den); num = wsum(num);
  if (lane == 0) score[node] = num / den;
}

__device__ __forceinline__ unsigned keymap(float s){
  unsigned u = __float_as_uint(s);
  return (u & 0x80000000u) ? ~u : (u | 0x80000000u);
}

__global__ __launch_bounds__(1024) void topk_k(const float* __restrict__ score,
                                               int* __restrict__ kept,
                                               float* __restrict__ tfac, int n, int k)
{
  const int t = threadIdx.x;
  constexpr int CH = 20;
  unsigned key[CH];
  float sc[CH];
  #pragma unroll
  for (int c = 0; c < CH; ++c) {
    const int i = c * 1024 + t;
    if (i < n) { const float s = score[i]; sc[c] = s; key[c] = keymap(s); }
    else       { sc[c] = 0.f; key[c] = 0u; }
  }
  __shared__ int cnt;
  __shared__ int sb[1024];
  __shared__ int carry_eq;
  unsigned vstar = 0u;
  for (int b = 31; b >= 0; --b) {
    const unsigned cand = vstar | (1u << b);
    if (t == 0) cnt = 0;
    __syncthreads();
    int local = 0;
    #pragma unroll
    for (int c = 0; c < CH; ++c) local += (key[c] >= cand) ? 1 : 0;
    local = wsumi(local);
    if ((t & 63) == 0) atomicAdd(&cnt, local);
    __syncthreads();
    if (cnt >= k) vstar = cand;
    __syncthreads();
  }
  if (t == 0) cnt = 0;
  __syncthreads();
  {
    int local = 0;
    #pragma unroll
    for (int c = 0; c < CH; ++c) local += (key[c] > vstar) ? 1 : 0;
    local = wsumi(local);
    if ((t & 63) == 0) atomicAdd(&cnt, local);
  }
  __syncthreads();
  const int need = k - cnt;
  if (t == 0) carry_eq = 0;
  __syncthreads();
  for (int c = 0; c < CH; ++c) {
    const int i = c * 1024 + t;
    const int flag = (i < n && key[c] == vstar) ? 1 : 0;
    sb[t] = flag;
    __syncthreads();
    for (int off = 1; off < 1024; off <<= 1) {
      const int v = (t >= off) ? sb[t - off] : 0;
      __syncthreads();
      sb[t] += v;
      __syncthreads();
    }
    const int rank = sb[t] - flag;
    const int tot = sb[1023];
    if (i < n) {
      const bool kp = (key[c] > vstar) || (flag && (carry_eq + rank) < need);
      kept[i] = kp ? 1 : 0;
      tfac[i] = kp ? tanhf(sc[c]) : 0.f;
    }
    __syncthreads();
    if (t == 0) carry_eq += tot;
    __syncthreads();
  }
}

__global__ void xpip_k(float* __restrict__ xs1, const float* __restrict__ tf, int total){
  const int i = blockIdx.x * 256 + threadIdx.x;
  if (i < total) xs1[i] *= tf[i >> 8];
}

__global__ __launch_bounds__(256) void flagsum_k(const int* __restrict__ kept,
    const int* __restrict__ ssrc, const int* __restrict__ sdst,
    int* __restrict__ bsum, int E){
  const int t = threadIdx.x;
  const int base = blockIdx.x * 1024;
  int loc = 0;
  #pragma unroll
  for (int j = 0; j < 4; ++j) {
    const int e = base + t * 4 + j;
    if (e < E) loc += kept[ssrc[e]] & kept[sdst[e]];
  }
  loc = wsumi(loc);
  __shared__ int wsh[4];
  if ((t & 63) == 0) wsh[t >> 6] = loc;
  __syncthreads();
  if (t == 0) bsum[blockIdx.x] = wsh[0] + wsh[1] + wsh[2] + wsh[3];
}

__global__ __launch_bounds__(512) void scanb_k(int* __restrict__ bsum, int nb, int* __restrict__ Ek){
  __shared__ int sb[512];
  const int t = threadIdx.x;
  const int v = (t < nb) ? bsum[t] : 0;
  sb[t] = v;
  __syncthreads();
  for (int off = 1; off < 512; off <<= 1) {
    const int u = (t >= off) ? sb[t - off] : 0;
    __syncthreads();
    sb[t] += u;
    __syncthreads();
  }
  if (t < nb) bsum[t] = sb[t] - v;
  if (t == 511) *Ek = sb[511];
}

__global__ __launch_bounds__(256) void compact_k(const int* __restrict__ kept,
    const int* __restrict__ ssrc, const int* __restrict__ sdst,
    const int* __restrict__ bsum, int* __restrict__ csrc, int* __restrict__ cdst,
    int* __restrict__ cidx, int* __restrict__ cntk, int E){
  const int t = threadIdx.x;
  const int base = blockIdx.x * 1024;
  int f[4]; int s = 0;
  #pragma unroll
  for (int j = 0; j < 4; ++j) {
    const int e = base + t * 4 + j;
    f[j] = (e < E) ? (kept[ssrc[e]] & kept[sdst[e]]) : 0;
    s += f[j];
  }
  __shared__ int sb[256];
  sb[t] = s;
  __syncthreads();
  for (int off = 1; off < 256; off <<= 1) {
    const int u = (t >= off) ? sb[t - off] : 0;
    __syncthreads();
    sb[t] += u;
    __syncthreads();
  }
  int pos = bsum[blockIdx.x] + sb[t] - s;
  #pragma unroll
  for (int j = 0; j < 4; ++j) {
    if (f[j]) {
      const int e = base + t * 4 + j;
      csrc[pos] = ssrc[e]; cdst[pos] = sdst[e]; cidx[pos] = e;
      atomicAdd(&cntk[sdst[e]], 1);
      ++pos;
    }
  }
}

__global__ void submerge_k(const float* __restrict__ x3, const float* __restrict__ xsum,
                           const int* __restrict__ cntk, const int* __restrict__ kept,
                           float* __restrict__ x32, int total){
  const int i = blockIdx.x * 256 + threadIdx.x;
  if (i >= total) return;
  const int v = i >> 7;
  float add = 0.f;
  if (kept[v]) {
    float c = (float)cntk[v];
    c = c > 0.f ? c : 1.f;
    add = frelu(xsum[i] / c);
  }
  x32[i] = x3[i] + add;
}

__global__ void fnode_k(const float* __restrict__ xsum, const float* __restrict__ recip,
                        const float* __restrict__ Wl1, const float* __restrict__ bl1,
                        float* __restrict__ out, int n){
  const int node = blockIdx.x * 4 + (threadIdx.x >> 6);
  const int lane = threadIdx.x & 63;
  if (node >= n) return;
  const float rc = recip[node];
  const float2 xv = *(const float2*)(xsum + (size_t)node * 128 + lane * 2);
  const float2 wv = *(const float2*)(Wl1 + lane * 2);
  float v = frelu(xv.x * rc) * wv.x + frelu(xv.y * rc) * wv.y;
  v = wsum(v);
  if (lane == 0) out[node] = 1.f / (1.f + expf(-(v + bl1[0])));
}

// ---------------------------------------------------------------- launch
extern "C" void kernel_launch(void* const* d_in, const int* in_sizes, int n_in,
                              void* d_out, int out_size, void* d_ws, size_t ws_size,
                              hipStream_t stream)
{
  const int N = N_NODES, E = N_EDGES;
  const float* node_feat = (const float*)d_in[0];
  const float* edge_feat = (const float*)d_in[1];
  const int*   eidx      = (const int*)d_in[2];
  const float* W_red = (const float*)d_in[3];  const float* b_red = (const float*)d_in[4];
  const float* W1 = (const float*)d_in[5];   const float* b1 = (const float*)d_in[6];
  const float* W2 = (const float*)d_in[7];   const float* b2 = (const float*)d_in[8];
  const float* W3 = (const float*)d_in[9];   const float* b3 = (const float*)d_in[10];
  const float* Wpre = (const float*)d_in[11]; const float* bpre = (const float*)d_in[12];
  const float* Wsub = (const float*)d_in[13]; const float* bsub = (const float*)d_in[14];
  const float* W4 = (const float*)d_in[15];  const float* b4 = (const float*)d_in[16];
  const float* Wg = (const float*)d_in[17];
  const float* a_s = (const float*)d_in[18]; const float* a_d = (const float*)d_in[19];
  const float* Wl1 = (const float*)d_in[20]; const float* bl1 = (const float*)d_in[21];
  const float* Ww = (const float*)d_in[22];  const float* bw = (const float*)d_in[23];
  float* out_x = (float*)d_out;
  float* out_w = out_x + N;

  char* wsb = (char*)d_ws;
  size_t off = 0;
  auto alloc = [&](size_t bytes) -> void* {
    void* p = wsb + off;
    off = (off + bytes + 255) & ~(size_t)255;
    return p;
  };
  float* u1   = (float*)alloc((size_t)E * 128 * 4);   // e1 -> e3a -> kept-es1(256-stride)
  float* u2   = (float*)alloc((size_t)E * 128 * 4);   // e2 -> e3
  float* n1   = (float*)alloc((size_t)N * 128 * 4);   // x0 -> x3a -> Psub -> x32
  float* n2   = (float*)alloc((size_t)N * 128 * 4);   // x1 -> x3
  float* n3   = (float*)alloc((size_t)N * 128 * 4);   // x2 -> Qsub
  float* xs1  = (float*)alloc((size_t)N * 256 * 4);
  float* P    = (float*)alloc((size_t)N * 256 * 4);
  float* Qb   = (float*)alloc((size_t)N * 256 * 4);
  float* xsum = (float*)alloc((size_t)N * 256 * 4);
  int* ssrc = (int*)alloc((size_t)E * 4);
  int* sdst = (int*)alloc((size_t)E * 4);
  int* seid = (int*)alloc((size_t)E * 4);
  int* csrc = (int*)alloc((size_t)E * 4);
  int* cdst = (int*)alloc((size_t)E * 4);
  int* cidx = (int*)alloc((size_t)E * 4);
  int* deg     = (int*)alloc((size_t)N * 4);
  int* cursor  = (int*)alloc((size_t)N * 4);
  int* rowstart= (int*)alloc((size_t)(N + 1) * 4);
  int* kept    = (int*)alloc((size_t)N * 4);
  int* cntk    = (int*)alloc((size_t)N * 4);
  float* recip = (float*)alloc((size_t)N * 4);
  float* hbuf  = (float*)alloc((size_t)N * 4);
  float* score = (float*)alloc((size_t)N * 4);
  float* tfac  = (float*)alloc((size_t)N * 4);
  int* bsum    = (int*)alloc(1024 * 4);
  int* Ek      = (int*)alloc(256);
  // split-fp16 transposed weights
  _Float16* w1Th = (_Float16*)alloc(128 * 128 * 2); _Float16* w1Tl = (_Float16*)alloc(128 * 128 * 2);
  _Float16* w2Th = (_Float16*)alloc(128 * 128 * 2); _Float16* w2Tl = (_Float16*)alloc(128 * 128 * 2);
  _Float16* w3Th = (_Float16*)alloc(128 * 256 * 2); _Float16* w3Tl = (_Float16*)alloc(128 * 256 * 2);
  _Float16* wpTh = (_Float16*)alloc(256 * 128 * 2); _Float16* wpTl = (_Float16*)alloc(256 * 128 * 2);
  _Float16* wsTh = (_Float16*)alloc(128 * 256 * 2); _Float16* wsTl = (_Float16*)alloc(128 * 256 * 2);
  _Float16* w4Th = (_Float16*)alloc(128 * 128 * 2); _Float16* w4Tl = (_Float16*)alloc(128 * 128 * 2);
  (void)ws_size; (void)in_sizes; (void)n_in; (void)out_size;

  const dim3 g128z(2, (N + 63) / 64, 2), g256z(4, (N + 63) / 64, 2);
  const dim3 g128(2, (N + 63) / 64);
  const int nbFS = (E + 1023) / 1024;
  const int gE = E / 64, gK = (EKCAP + 63) / 64;
  #define NIL3 nullptr, nullptr, nullptr

  // ---- weight splits ----
  wsplit_k<<<(128 * 128) / 256, 256, 0, stream>>>(W1 + 256 * 128, 128, 128, w1Th, w1Tl);
  wsplit_k<<<(128 * 128) / 256, 256, 0, stream>>>(W2 + 256 * 128, 128, 128, w2Th, w2Tl);
  wsplit_k<<<(256 * 128) / 256, 256, 0, stream>>>(W3 + 512 * 128, 256, 128, w3Th, w3Tl);
  wsplit_k<<<(128 * 256) / 256, 256, 0, stream>>>(Wpre + 256 * 256, 128, 256, wpTh, wpTl);
  wsplit_k<<<(256 * 128) / 256, 256, 0, stream>>>(Wsub + 512 * 128, 256, 128, wsTh, wsTl);
  wsplit_k<<<(128 * 128) / 256, 256, 0, stream>>>(W4 + 512 * 128, 128, 128, w4Th, w4Tl);

  // ---- sort edges by dst (counting sort) ----
  hipMemsetAsync(deg, 0, (size_t)N * 4, stream);
  hist_k<<<(E + 255) / 256, 256, 0, stream>>>(eidx + E, deg, E);
  scan_deg_k<<<1, 1024, 0, stream>>>(deg, rowstart, cursor, recip, N);
  scatter_k<<<(E + 255) / 256, 256, 0, stream>>>(eidx, eidx + E, cursor, ssrc, sdst, seid, E);

  // ---- x0 -> n1 ----
  sgemm_k<<<g128, 256, 0, stream>>>(node_feat, 256, W_red, b_red, n1, N, 128);

  // ---- conv1: ein=edge_feat (gather), out u1; x1 -> n2 ----
  sgemm2_k<<<g128z, 256, 0, stream>>>(n1, 128, W1, W1 + 128 * 128,
                                      nullptr, 0, nullptr, nullptr, b1, P, Qb, N, 128);
  hipMemsetAsync(xsum, 0, (size_t)N * 128 * 4, stream);
  econv_m<false, true, true, false, false, true><<<gE, 256, 0, stream>>>(
      edge_feat, nullptr, 128, w1Th, w1Tl, P, Qb, 128, ssrc, sdst, seid, seid, nullptr,
      u1, 128, xsum, 128, NIL3);
  meanrelu_k<<<(N * 128) / 256, 256, 0, stream>>>(xsum, recip, n2, N * 128, 7);

  // ---- conv2: ein=u1(e1), out u2; x2 -> n3 ----
  sgemm2_k<<<g128z, 256, 0, stream>>>(n2, 128, W2, W2 + 128 * 128,
                                      nullptr, 0, nullptr, nullptr, b2, P, Qb, N, 128);
  hipMemsetAsync(xsum, 0, (size_t)N * 128 * 4, stream);
  econv_m<true, false, true, false, false, true><<<gE, 256, 0, stream>>>(
      u1, nullptr, 128, w2Th, w2Tl, P, Qb, 128, ssrc, sdst, nullptr, nullptr, nullptr,
      u2, 128, xsum, 128, NIL3);
  meanrelu_k<<<(N * 128) / 256, 256, 0, stream>>>(xsum, recip, n3, N * 128, 7);

  // ---- conv3a: ein=[e2(u2), e1(u1)]; e3a overwrites u1; x3a -> n1 ----
  sgemm2_k<<<g128z, 256, 0, stream>>>(n3, 128, W3, W3 + 256 * 128,
                                      n2, 128, W3 + 128 * 128, W3 + 384 * 128, b3, P, Qb, N, 128);
  hipMemsetAsync(xsum, 0, (size_t)N * 128 * 4, stream);
  econv_m<true, false, true, false, false, true><<<gE, 256, 0, stream>>>(
      u2, u1, 128, w3Th, w3Tl, P, Qb, 128, ssrc, sdst, nullptr, nullptr, nullptr,
      u1, 128, xsum, 128, NIL3);
  meanrelu_k<<<(N * 128) / 256, 256, 0, stream>>>(xsum, recip, n1, N * 128, 7);

  // ---- conv3b (shared W3): ein=[e3a(u1), e2(u2)]; e3 overwrites u2; x3 -> n2 ----
  sgemm2_k<<<g128z, 256, 0, stream>>>(n1, 128, W3, W3 + 256 * 128,
                                      n3, 128, W3 + 128 * 128, W3 + 384 * 128, b3, P, Qb, N, 128);
  hipMemsetAsync(xsum, 0, (size_t)N * 128 * 4, stream);
  econv_m<true, false, true, false, false, true><<<gE, 256, 0, stream>>>(
      u1, u2, 128, w3Th, w3Tl, P, Qb, 128, ssrc, sdst, nullptr, nullptr, nullptr,
      u2, 128, xsum, 128, NIL3);
  meanrelu_k<<<(N * 128) / 256, 256, 0, stream>>>(xsum, recip, n2, N * 128, 7);

  // ---- pre conv (NOUT=256 via two 128-col halves), aggregate only ----
  sgemm2_k<<<g256z, 256, 0, stream>>>(n2, 128, Wpre, Wpre + 128 * 256,
                                      nullptr, 0, nullptr, nullptr, bpre, P, Qb, N, 256);
  hipMemsetAsync(xsum, 0, (size_t)N * 256 * 4, stream);
  econv_m<true, false, false, false, false, true><<<gE, 256, 0, stream>>>(
      u2, nullptr, 128, wpTh, wpTl, P, Qb, 256, ssrc, sdst, nullptr, nullptr, nullptr,
      nullptr, 0, xsum, 256, NIL3);
  econv_m<true, false, false, false, false, true><<<gE, 256, 0, stream>>>(
      u2, nullptr, 128, wpTh + 128 * 128, wpTl + 128 * 128, P + 128, Qb + 128, 256,
      ssrc, sdst, nullptr, nullptr, nullptr, nullptr, 0, xsum + 128, 256, NIL3);
  meanrelu_k<<<(N * 256) / 256, 256, 0, stream>>>(xsum, recip, xs1, N * 256, 8);

  // ---- SAGPool scorer + top-k; xp in-place over xs1 ----
  h_k<<<(N + 3) / 4, 256, 0, stream>>>(xs1, Wg, hbuf, N);
  att_k<<<(N + 3) / 4, 256, 0, stream>>>(hbuf, rowstart, ssrc, a_s, a_d, score, N);
  topk_k<<<1, 1024, 0, stream>>>(score, kept, tfac, N, N / 2);
  xpip_k<<<(N * 256) / 256, 256, 0, stream>>>(xs1, tfac, N * 256);

  // ---- compact kept edges ----
  hipMemsetAsync(cntk, 0, (size_t)N * 4, stream);
  flagsum_k<<<nbFS, 256, 0, stream>>>(kept, ssrc, sdst, bsum, E);
  scanb_k<<<1, 512, 0, stream>>>(bsum, nbFS, Ek);
  compact_k<<<nbFS, 256, 0, stream>>>(kept, ssrc, sdst, bsum, csrc, cdst, cidx, cntk, E);

  // ---- sub conv: Psub -> n1, Qsub -> n3 ----
  sgemm2_k<<<g128z, 256, 0, stream>>>(xs1, 256, Wsub, Wsub + 256 * 128,
                                      nullptr, 0, nullptr, nullptr, bsub, n1, n3, N, 128);
  // presub: recompute es1 (raw, 256-stride into u1) for kept edges, two halves
  econv_m<true, true, true, false, true, false><<<gK, 256, 0, stream>>>(
      u2, nullptr, 128, wpTh, wpTl, P, Qb, 256, csrc, cdst, cidx, nullptr, Ek,
      u1, 256, nullptr, 0, NIL3);
  econv_m<true, true, true, false, true, false><<<gK, 256, 0, stream>>>(
      u2, nullptr, 128, wpTh + 128 * 128, wpTl + 128 * 128, P + 128, Qb + 128, 256,
      csrc, cdst, cidx, nullptr, Ek, u1 + 128, 256, nullptr, 0, NIL3);
  hipMemsetAsync(xsum, 0, (size_t)N * 128 * 4, stream);
  econv_m<true, false, false, false, true, true><<<gK, 256, 0, stream>>>(
      u1, u1 + 128, 256, wsTh, wsTl, n1, n3, 128, csrc, cdst, nullptr, nullptr, Ek,
      nullptr, 0, xsum, 128, NIL3);
  submerge_k<<<(N * 128) / 256, 256, 0, stream>>>(n2, xsum, cntk, kept, n1, N * 128);

  // ---- conv4: ein=e3(u2); fused w-head ----
  sgemm2_k<<<g128z, 256, 0, stream>>>(n1, 128, W4, W4 + 256 * 128,
                                      n2, 128, W4 + 128 * 128, W4 + 384 * 128, b4, P, Qb, N, 128);
  hipMemsetAsync(xsum, 0, (size_t)N * 128 * 4, stream);
  econv_m<true, false, false, true, false, true><<<gE, 256, 0, stream>>>(
      u2, nullptr, 128, w4Th, w4Tl, P, Qb, 128, ssrc, sdst, nullptr, seid, nullptr,
      nullptr, 0, xsum, 128, Ww, bw, out_w);

  // ---- node head ----
  fnode_k<<<(N + 3) / 4, 256, 0, stream>>>(xsum, recip, Wl1, bl1, out_x, N);
  #undef NIL3
}